// Round 3
// 17088.248 us; speedup vs baseline: 1.2573x; 1.2573x over previous
//
#include <hip/hip_runtime.h>
#include <math.h>

// ---------------------------------------------------------------------------
// Model_49675591746044: VQ + 6-layer post-LN transformer decoder.
// Round 7 (= round-6 resubmit; round-6 bench was an infra failure, kernel
// never ran). k_vq_score v2: MFMA distance GEMM + fused top-16, reg->LDS
// staging (ds_write_b128) into a PADDED un-swizzled layout (144 B rows).
// Round-5's global_load_lds used a per-lane-divergent LDS pointer (uniformity
// not provable -> possible waterfall => double lane offset => scrambled LDS);
// v2 removes that mechanism entirely. lo-plane MFMAs skipped for bf16 inputs
// (flag is wave-uniform; xlo==0 exactly). Rest identical to round-4 passing.
// ---------------------------------------------------------------------------

#define THREEFRY_PARTITIONABLE 1

typedef unsigned short u16;
typedef unsigned int   u32;
typedef unsigned long long u64;

typedef short bf16x8 __attribute__((ext_vector_type(8)));
typedef float f32x4  __attribute__((ext_vector_type(4)));
typedef u16   u16x8  __attribute__((ext_vector_type(8)));

constexpr int NB  = 16;
constexpr int NS  = 512;
constexpr int ND  = 768;
constexpr int NK  = 8192;
constexpr int NH  = 8;
constexpr int NL  = 6;
constexpr int NF  = 2048;
constexpr int NTOK = NB * NS;   // 8192
constexpr int NDH  = ND / NH;   // 96
#define NEGV (-1e9f)

// VQ MFMA kernel geometry
constexpr int VQ_SPLIT = 4;              // code-range splits (grid.y)
constexpr int VQ_CPS   = NK / VQ_SPLIT;  // 2048 codes per split
constexpr int VQ_TILES = VQ_CPS / 128;   // 16 N-tiles of 128 codes

// LDS byte offsets for k_vq_score (bf16 rows padded 64->72 elems = 144 B)
constexpr int L_AHI = 0;                  // 32 rows * 144 B = 4608
constexpr int L_ALO = 4608;               // 32 rows * 144 B = 4608
constexpr int L_B   = 9216;               // 128 rows * 144 B = 18432
constexpr int L_SC  = 27648;              // 32*128 f32       = 16384
constexpr int L_TOT = 44032;

__device__ __forceinline__ float b2f(u16 u) { return __uint_as_float(((u32)u) << 16); }
__device__ __forceinline__ u16 f2b(float f) {
  u32 u = __float_as_uint(f);
  u32 r = (u + 0x7FFFu + ((u >> 16) & 1u)) >> 16;
  return (u16)r;
}
__device__ __forceinline__ float ldv(const void* p, size_t i, int isbf) {
  return isbf ? b2f(((const u16*)p)[i]) : ((const float*)p)[i];
}

// ---------------- dtype detection ----------------
__global__ void k_detect(const void* x, int* flag) {
  if (threadIdx.x == 0 && blockIdx.x == 0) {
    const u16* p = (const u16*)x;
    int wild = 0;
    for (int i = 0; i < 1024; i++) {
      u16 u = p[i];
      u32 e = (u >> 7) & 0xFF;
      if (!(u == 0 || u == 0x8000u || (e >= 100 && e <= 134))) wild++;
    }
    *flag = (wild < 64) ? 1 : 0;   // 1 = bf16 inputs
  }
}

// ---------------- reductions (blockDim.x == 256) ----------------
__device__ __forceinline__ float blockReduceSum256(float v, float* s) {
  int t = threadIdx.x;
  s[t] = v; __syncthreads();
  #pragma unroll
  for (int off = 128; off > 0; off >>= 1) {
    if (t < off) s[t] += s[t + off];
    __syncthreads();
  }
  float r = s[0]; __syncthreads();
  return r;
}

// ---------------- pad mask + z_e (fp32) + hi/lo bf16 planes ----------------
__global__ __launch_bounds__(256) void k_pad_z(
    const void* __restrict__ x, float* __restrict__ z,
    float* __restrict__ xn2, int* __restrict__ padf,
    u16* __restrict__ xhi, u16* __restrict__ xlo,
    const int* __restrict__ flag) {
  __shared__ float sred[256];
  int r = blockIdx.x, t = threadIdx.x;
  int isbf = *flag;
  size_t base = (size_t)r * ND;
  float a0 = ldv(x, base + t, isbf);
  float a1 = ldv(x, base + t + 256, isbf);
  float a2 = ldv(x, base + t + 512, isbf);
  float ss = blockReduceSum256(a0 * a0 + a1 * a1 + a2 * a2, sred);
  int pad = (sqrtf(ss) <= 1e-6f) ? 1 : 0;
  if (pad) { a0 = 0.f; a1 = 0.f; a2 = 0.f; }
  float* zr = z + base;
  zr[t] = a0; zr[t + 256] = a1; zr[t + 512] = a2;
  u16 h0 = f2b(a0), h1 = f2b(a1), h2 = f2b(a2);
  xhi[base + t] = h0; xhi[base + t + 256] = h1; xhi[base + t + 512] = h2;
  xlo[base + t]       = f2b(a0 - b2f(h0));
  xlo[base + t + 256] = f2b(a1 - b2f(h1));
  xlo[base + t + 512] = f2b(a2 - b2f(h2));
  if (t == 0) { xn2[r] = pad ? 0.f : ss; padf[r] = pad; }
}

// ---------------- codebook -> fp32 copy + bf16 copy + |c|^2 ----------------
__global__ __launch_bounds__(256) void k_cb(
    const void* __restrict__ cb, float* __restrict__ cbf, float* __restrict__ cn2,
    u16* __restrict__ cbh, const int* __restrict__ flag) {
  __shared__ float sred[256];
  int r = blockIdx.x, t = threadIdx.x;
  int isbf = *flag;
  size_t base = (size_t)r * ND;
  float a0 = ldv(cb, base + t, isbf);
  float a1 = ldv(cb, base + t + 256, isbf);
  float a2 = ldv(cb, base + t + 512, isbf);
  float* o = cbf + base;
  o[t] = a0; o[t + 256] = a1; o[t + 512] = a2;
  cbh[base + t] = f2b(a0); cbh[base + t + 256] = f2b(a1); cbh[base + t + 512] = f2b(a2);
  float ss = blockReduceSum256(a0 * a0 + a1 * a1 + a2 * a2, sred);
  if (t == 0) cn2[r] = ss;
}

// ---------------- top-16 insertion (running worst at wslot) ----------------
#define VQ_INSERT(dt, kk)                                                    \
  if ((dt) < wv) {                                                           \
    _Pragma("unroll")                                                        \
    for (int j = 0; j < 16; j++)                                             \
      if (j == wslot) { bestv[j] = (dt); besti[j] = (kk); }                  \
    wv = bestv[0]; wslot = 0;                                                \
    _Pragma("unroll")                                                        \
    for (int j = 1; j < 16; j++)                                             \
      if (bestv[j] > wv) { wv = bestv[j]; wslot = j; }                       \
  }

// ---------------- VQ scores via bf16 MFMA, fused top-16 --------------------
// Block: 32 query rows x one code split (2048 codes in 16 tiles of 128).
// key = cn2[c] - 2*(xhi.c [+ xlo.c]); acc init = -0.5*cn2 so key = -2*acc.
// Staging: plain reg->LDS ds_write_b128, padded rows (144 B), no swizzle.
__global__ __launch_bounds__(256) void k_vq_score(
    const u16* __restrict__ xhi, const u16* __restrict__ xlo,
    const u16* __restrict__ cbh, const float* __restrict__ cn2,
    const int* __restrict__ flag,
    float* __restrict__ candv, int* __restrict__ candi) {
  __shared__ __align__(16) char lds[L_TOT];
  const int t = threadIdx.x;
  const int l = t & 63, w = t >> 6;
  const int rowbase = blockIdx.x * 32;
  const int split = blockIdx.y;
  const int dolo = (*flag) == 0;           // fp32 inputs need the lo plane

  // --- staging assignments (thread-constant) ---
  const int arow = t >> 3, aslot = t & 7;  // A: 32 rows x 8 chunks = 256
  const size_t srcA = (size_t)(rowbase + arow) * ND + aslot * 8;
  const int dstA = arow * 144 + aslot * 16;
  // B: 128 codes x 8 chunks = 1024 = 4 x 256; chunk j*256+t -> code j*32+(t>>3)
  const int c0 = (t >> 3), c1 = 32 + c0, c2 = 64 + c0, c3 = 96 + c0;
  const int dstB0 = L_B + c0 * 144 + aslot * 16;
  const int dstB1 = L_B + c1 * 144 + aslot * 16;
  const int dstB2 = L_B + c2 * 144 + aslot * 16;
  const int dstB3 = L_B + c3 * 144 + aslot * 16;

  // --- MFMA fragment read offsets, constant per lane ---
  // A operand: lane -> row (l&15), k-chunk ks*4+(l>>4)  [16x16x32 bf16]
  int aoff[2][2], boff[2][2];
  #pragma unroll
  for (int mi = 0; mi < 2; mi++)
    #pragma unroll
    for (int ks = 0; ks < 2; ks++)
      aoff[mi][ks] = (mi * 16 + (l & 15)) * 144 + (ks * 4 + (l >> 4)) * 16;
  #pragma unroll
  for (int ni = 0; ni < 2; ni++)
    #pragma unroll
    for (int ks = 0; ks < 2; ks++)
      boff[ni][ks] = L_B + (w * 32 + ni * 16 + (l & 15)) * 144 + (ks * 4 + (l >> 4)) * 16;

  float* scores = (float*)(lds + L_SC);    // [32][128] f32

  float bestv[16]; int besti[16];
  #pragma unroll
  for (int j = 0; j < 16; j++) { bestv[j] = 3.4e38f; besti[j] = 0; }
  float wv = 3.4e38f; int wslot = 0;

  for (int tile = 0; tile < VQ_TILES; tile++) {
    const int codebase = split * VQ_CPS + tile * 128;
    f32x4 acc[2][2];
    #pragma unroll
    for (int ni = 0; ni < 2; ni++) {
      float cv = -0.5f * cn2[codebase + w * 32 + ni * 16 + (l & 15)];
      f32x4 ini = {cv, cv, cv, cv};
      acc[0][ni] = ini; acc[1][ni] = ini;
    }
    const u16* pB0 = cbh + (size_t)(codebase + c0) * ND + aslot * 8;
    const u16* pB1 = cbh + (size_t)(codebase + c1) * ND + aslot * 8;
    const u16* pB2 = cbh + (size_t)(codebase + c2) * ND + aslot * 8;
    const u16* pB3 = cbh + (size_t)(codebase + c3) * ND + aslot * 8;

    for (int kc = 0; kc < 12; kc++) {            // 12 x BK=64
      const int ko = kc * 64;
      u16x8 vah = *(const u16x8*)(xhi + srcA + ko);
      u16x8 valr = {};
      if (dolo) valr = *(const u16x8*)(xlo + srcA + ko);
      u16x8 vb0 = *(const u16x8*)(pB0 + ko);
      u16x8 vb1 = *(const u16x8*)(pB1 + ko);
      u16x8 vb2 = *(const u16x8*)(pB2 + ko);
      u16x8 vb3 = *(const u16x8*)(pB3 + ko);
      __syncthreads();                           // prev kc's LDS reads done
      *(u16x8*)(lds + dstA) = vah;
      if (dolo) *(u16x8*)(lds + L_ALO + dstA) = valr;
      *(u16x8*)(lds + dstB0) = vb0;
      *(u16x8*)(lds + dstB1) = vb1;
      *(u16x8*)(lds + dstB2) = vb2;
      *(u16x8*)(lds + dstB3) = vb3;
      __syncthreads();                           // stores visible
      #pragma unroll
      for (int ks = 0; ks < 2; ks++) {
        bf16x8 b0  = *(const bf16x8*)(lds + boff[0][ks]);
        bf16x8 b1  = *(const bf16x8*)(lds + boff[1][ks]);
        bf16x8 ah0 = *(const bf16x8*)(lds + aoff[0][ks]);
        bf16x8 ah1 = *(const bf16x8*)(lds + aoff[1][ks]);
        acc[0][0] = __builtin_amdgcn_mfma_f32_16x16x32_bf16(ah0, b0, acc[0][0], 0, 0, 0);
        acc[1][0] = __builtin_amdgcn_mfma_f32_16x16x32_bf16(ah1, b0, acc[1][0], 0, 0, 0);
        acc[0][1] = __builtin_amdgcn_mfma_f32_16x16x32_bf16(ah0, b1, acc[0][1], 0, 0, 0);
        acc[1][1] = __builtin_amdgcn_mfma_f32_16x16x32_bf16(ah1, b1, acc[1][1], 0, 0, 0);
        if (dolo) {
          bf16x8 al0 = *(const bf16x8*)(lds + L_ALO + aoff[0][ks]);
          bf16x8 al1 = *(const bf16x8*)(lds + L_ALO + aoff[1][ks]);
          acc[0][0] = __builtin_amdgcn_mfma_f32_16x16x32_bf16(al0, b0, acc[0][0], 0, 0, 0);
          acc[1][0] = __builtin_amdgcn_mfma_f32_16x16x32_bf16(al1, b0, acc[1][0], 0, 0, 0);
          acc[0][1] = __builtin_amdgcn_mfma_f32_16x16x32_bf16(al0, b1, acc[0][1], 0, 0, 0);
          acc[1][1] = __builtin_amdgcn_mfma_f32_16x16x32_bf16(al1, b1, acc[1][1], 0, 0, 0);
        }
      }
    }
    // write keys: C/D layout col=lane&15, row=(lane>>4)*4+reg  [m89/m91]
    #pragma unroll
    for (int mi = 0; mi < 2; mi++)
      #pragma unroll
      for (int ni = 0; ni < 2; ni++)
        #pragma unroll
        for (int r = 0; r < 4; r++) {
          int srow = mi * 16 + (l >> 4) * 4 + r;
          int scol = w * 32 + ni * 16 + (l & 15);
          scores[srow * 128 + scol] = -2.0f * acc[mi][ni][r];
        }
    __syncthreads();
    {
      int irow = t >> 3, isub = t & 7;
      const float* srow = scores + irow * 128;
      #pragma unroll
      for (int i = 0; i < 16; i++) {
        int c = isub + i * 8;
        float key = srow[c];
        int gk = codebase + c;
        VQ_INSERT(key, gk)
      }
    }
    __syncthreads();
  }

  // --- in-block merge: 8 partial top-16 per row -> 16 ---
  float* svals = (float*)lds;                    // 32*128 f32
  int*   sidx  = (int*)(lds + 16384);            // 32*128 int
  {
    int irow = t >> 3, isub = t & 7;
    #pragma unroll
    for (int j = 0; j < 16; j++) {
      svals[irow * 128 + isub * 16 + j] = bestv[j];
      sidx [irow * 128 + isub * 16 + j] = besti[j];
    }
  }
  __syncthreads();
  if (t < 32) {
    float bv[16]; int bi[16]; float w2 = 3.4e38f; int ws2 = 0;
    #pragma unroll
    for (int j = 0; j < 16; j++) { bv[j] = 3.4e38f; bi[j] = 0; }
    const float* sv = svals + t * 128;
    const int*   si = sidx  + t * 128;
    for (int i = 0; i < 128; i++) {
      float dv = sv[i];
      if (dv < w2) {
        int ii = si[i];
        #pragma unroll
        for (int j = 0; j < 16; j++)
          if (j == ws2) { bv[j] = dv; bi[j] = ii; }
        w2 = bv[0]; ws2 = 0;
        #pragma unroll
        for (int j = 1; j < 16; j++)
          if (bv[j] > w2) { w2 = bv[j]; ws2 = j; }
      }
    }
    float* ov = candv + ((size_t)(rowbase + t) * VQ_SPLIT + split) * 16;
    int*   oi = candi + ((size_t)(rowbase + t) * VQ_SPLIT + split) * 16;
    #pragma unroll
    for (int j = 0; j < 16; j++) { ov[j] = bv[j]; oi[j] = bi[j]; }
  }
}

// ---------------- merge across splits: 64 candidates -> 16 ----------------
__global__ __launch_bounds__(256) void k_vq_merge(
    const float* __restrict__ candv, const int* __restrict__ candi,
    int* __restrict__ cand) {
  int row = blockIdx.x * 256 + threadIdx.x;
  float bestv[16]; int besti[16];
  #pragma unroll
  for (int j = 0; j < 16; j++) { bestv[j] = 3.4e38f; besti[j] = 0; }
  float wv = 3.4e38f; int wslot = 0;
  const float* sv = candv + (size_t)row * 64;
  const int*   si = candi + (size_t)row * 64;
  for (int i = 0; i < 64; i++) {
    float dv = sv[i]; int ii = si[i];
    VQ_INSERT(dv, ii)
  }
  int* o = cand + (size_t)row * 16;
  #pragma unroll
  for (int j = 0; j < 16; j++) o[j] = besti[j];
}

// ---------------- threefry2x32, key (0, 42) ----------------
__device__ __forceinline__ void threefry2x32_042(u32 c0, u32 c1, u32& o0, u32& o1) {
  const u32 K0 = 0u, K1 = 42u, K2 = 0u ^ 42u ^ 0x1BD11BDAu;
  u32 x0 = c0 + K0, x1 = c1 + K1;
  #define TF_R(r) { x0 += x1; x1 = (x1 << (r)) | (x1 >> (32 - (r))); x1 ^= x0; }
  TF_R(13) TF_R(15) TF_R(26) TF_R(6)   x0 += K1; x1 += K2 + 1u;
  TF_R(17) TF_R(29) TF_R(16) TF_R(24)  x0 += K2; x1 += K0 + 2u;
  TF_R(13) TF_R(15) TF_R(26) TF_R(6)   x0 += K0; x1 += K1 + 3u;
  TF_R(17) TF_R(29) TF_R(16) TF_R(24)  x0 += K1; x1 += K2 + 4u;
  TF_R(13) TF_R(15) TF_R(26) TF_R(6)   x0 += K2; x1 += K0 + 5u;
  #undef TF_R
  o0 = x0; o1 = x1;
}

__device__ __forceinline__ u32 jax_bits(u32 e) {
  u32 b0, b1;
#if THREEFRY_PARTITIONABLE
  threefry2x32_042(0u, e, b0, b1);
  return b0 ^ b1;
#else
  const u32 HALF = (u32)(NTOK * 10 / 2);
  if (e < HALF) { threefry2x32_042(e, e + HALF, b0, b1); return b0; }
  else          { threefry2x32_042(e - HALF, e, b0, b1); return b1; }
#endif
}

// ---------------- VQ refine (fp64) + gumbel choose + write quantized --------
__global__ __launch_bounds__(64) void k_vq_choose(
    const float* __restrict__ z, const float* __restrict__ cbf,
    const int* __restrict__ cand, float* __restrict__ h) {
  __shared__ double s_xc[64], s_c2[64];
  __shared__ double dvals[16]; __shared__ int didx[16];
  __shared__ int s_enc;
  __shared__ double s_x2v;
  int r = blockIdx.x, t = threadIdx.x;
  int c = t >> 2, p = t & 3;
  int idx = cand[(size_t)r * 16 + c];
  const float* xr = z + (size_t)r * ND;
  const float* cr = cbf + (size_t)idx * ND;
  double xc = 0.0, c2 = 0.0;
  for (int d = p * 192; d < p * 192 + 192; d++) {
    double xv = (double)xr[d], cv = (double)cr[d];
    xc += xv * cv; c2 += cv * cv;
  }
  s_xc[t] = xc; s_c2[t] = c2;
  __syncthreads();
  if (t == 0) {
    double sx2 = 0;
    for (int d = 0; d < ND; d++) { double xv = (double)xr[d]; sx2 += xv * xv; }
    s_x2v = sx2;
  }
  __syncthreads();
  if (t < 16) {
    double sxc = 0, sc2 = 0;
    for (int pp = 0; pp < 4; pp++) { sxc += s_xc[t * 4 + pp]; sc2 += s_c2[t * 4 + pp]; }
    dvals[t] = s_x2v + sc2 - 2.0 * sxc;
    didx[t]  = cand[(size_t)r * 16 + t];
  }
  __syncthreads();
  if (t == 0) {
    double dv[16]; int di[16];
    for (int j = 0; j < 16; j++) { dv[j] = dvals[j]; di[j] = didx[j]; }
    for (int a = 1; a < 16; a++) {
      double vv = dv[a]; int ii = di[a]; int b = a;
      while (b > 0 && (dv[b-1] > vv || (dv[b-1] == vv && di[b-1] > ii))) {
        dv[b] = dv[b-1]; di[b] = di[b-1]; b--;
      }
      dv[b] = vv; di[b] = ii;
    }
    double bestsc = -1e300; int bestj = 0;
    for (int j = 0; j < 10; j++) {
      u32 e = (u32)(r * 10 + j);
      u32 bits = jax_bits(e);
      u32 fb = (bits >> 9) | 0x3f800000u;
      float uf = __uint_as_float(fb) - 1.0f;
      float vf = uf + 1e-10f;
      vf = fmaxf(1e-10f, vf);
      double g = -log(-log((double)vf));
      double sc = -dv[j] + g;
      if (sc > bestsc) { bestsc = sc; bestj = j; }
    }
    s_enc = di[bestj];
  }
  __syncthreads();
  int enc = s_enc;
  const float* qv = cbf + (size_t)enc * ND;
  float* hr = h + (size_t)r * ND;
  for (int d = t; d < ND; d += 64) hr[d] = qv[d];
}

// ---------------- GEMM: C = A[M,K]fp32 * Bw[N,K]^T + bias ----------------
__global__ __launch_bounds__(256) void k_gemm_nt(
    const float* __restrict__ A, const void* __restrict__ Bw, u64 boff,
    const void* __restrict__ bias, u64 bioff, void* __restrict__ Cv,
    int M, int N, int Kd, int lda, int ldb, int ldc, int relu, int outIsInputDtype,
    const int* __restrict__ flag) {
  __shared__ float As[16][68];
  __shared__ float Bs[16][68];
  int isbf = *flag;
  int tid = threadIdx.x;
  int tx = tid & 15, ty = tid >> 4;
  int m0 = blockIdx.y * 64, n0 = blockIdx.x * 64;
  int la_m = tid >> 2, la_k = (tid & 3) * 4;
  const float* Aptr = A + (size_t)(m0 + la_m) * lda + la_k;
  const u16*   B16 = (const u16*)Bw + boff + (size_t)(n0 + la_m) * ldb + la_k;
  const float* B32 = (const float*)Bw + boff + (size_t)(n0 + la_m) * ldb + la_k;
  float acc[4][4] = {};
  for (int kt = 0; kt < Kd; kt += 16) {
    float4 av = *(const float4*)(Aptr + kt);
    float b0, b1, b2, b3;
    if (isbf) {
      ushort4 bu = *(const ushort4*)(B16 + kt);
      b0 = b2f(bu.x); b1 = b2f(bu.y); b2 = b2f(bu.z); b3 = b2f(bu.w);
    } else {
      float4 bf4 = *(const float4*)(B32 + kt);
      b0 = bf4.x; b1 = bf4.y; b2 = bf4.z; b3 = bf4.w;
    }
    As[la_k + 0][la_m] = av.x; As[la_k + 1][la_m] = av.y;
    As[la_k + 2][la_m] = av.z; As[la_k + 3][la_m] = av.w;
    Bs[la_k + 0][la_m] = b0; Bs[la_k + 1][la_m] = b1;
    Bs[la_k + 2][la_m] = b2; Bs[la_k + 3][la_m] = b3;
    __syncthreads();
    #pragma unroll
    for (int k = 0; k < 16; k++) {
      float4 a4 = *(const float4*)(&As[k][ty * 4]);
      float4 b4 = *(const float4*)(&Bs[k][tx * 4]);
      float a[4] = {a4.x, a4.y, a4.z, a4.w};
      float b[4] = {b4.x, b4.y, b4.z, b4.w};
      #pragma unroll
      for (int i = 0; i < 4; i++)
        #pragma unroll
        for (int j = 0; j < 4; j++) acc[i][j] += a[i] * b[j];
    }
    __syncthreads();
  }
  float bv[4];
  #pragma unroll
  for (int j = 0; j < 4; j++) bv[j] = ldv(bias, bioff + n0 + tx * 4 + j, isbf);
  #pragma unroll
  for (int i = 0; i < 4; i++) {
    int cm = m0 + ty * 4 + i;
    float v[4];
    #pragma unroll
    for (int j = 0; j < 4; j++) {
      v[j] = acc[i][j] + bv[j];
      if (relu) v[j] = fmaxf(v[j], 0.f);
    }
    if (outIsInputDtype && isbf) {
      u16* Cb = (u16*)Cv;
      ushort4 o4 = { f2b(v[0]), f2b(v[1]), f2b(v[2]), f2b(v[3]) };
      *(ushort4*)(Cb + (size_t)cm * ldc + n0 + tx * 4) = o4;
    } else {
      float* C = (float*)Cv;
      float4 o4 = { v[0], v[1], v[2], v[3] };
      *(float4*)(C + (size_t)cm * ldc + n0 + tx * 4) = o4;
    }
  }
}

// ---------------- flash attention: O = softmax(QK^T/sqrt(dh)+bias) V --------
__global__ __launch_bounds__(256) void k_flash(
    const float* __restrict__ qkv, const int* __restrict__ padf,
    float* __restrict__ attO, int selfmask) {
  __shared__ float Qs[64][97];
  __shared__ float Ks[32][97];
  __shared__ float Vs[32][97];
  __shared__ float Ps[64][33];
  __shared__ float row_m[64], row_l[64], kbias[32];
  int zb = blockIdx.y; int b = zb >> 3, hh = zb & 7;
  int m0 = blockIdx.x * 64;
  int tid = threadIdx.x, tx = tid & 15, ty = tid >> 4;
  const float* Qb = qkv + (size_t)b * NS * (3 * ND) + hh * NDH;
  const float* Kb = Qb + ND;
  const float* Vb = Qb + 2 * ND;
  for (int e = tid; e < 64 * 96; e += 256) {
    int r = e / 96, c = e - r * 96;
    Qs[r][c] = Qb[(size_t)(m0 + r) * (3 * ND) + c];
  }
  if (tid < 64) { row_m[tid] = -3.0e38f; row_l[tid] = 0.f; }
  __syncthreads();
  float o[4][6];
  #pragma unroll
  for (int i = 0; i < 4; i++)
    #pragma unroll
    for (int j = 0; j < 6; j++) o[i][j] = 0.f;
  const float sq = sqrtf(96.0f);

  for (int kt = 0; kt < NS; kt += 32) {
    for (int e = tid; e < 32 * 96; e += 256) {
      int r = e / 96, c = e - r * 96;
      Ks[r][c] = Kb[(size_t)(kt + r) * (3 * ND) + c];
      Vs[r][c] = Vb[(size_t)(kt + r) * (3 * ND) + c];
    }
    if (tid < 32) kbias[tid] = padf[b * NS + kt + tid] ? NEGV : 0.f;
    __syncthreads();

    float s[4][2];
    #pragma unroll
    for (int i = 0; i < 4; i++) { s[i][0] = 0.f; s[i][1] = 0.f; }
    for (int d = 0; d < 96; d++) {
      float b0 = Ks[tx * 2 + 0][d], b1 = Ks[tx * 2 + 1][d];
      #pragma unroll
      for (int i = 0; i < 4; i++) {
        float a = Qs[ty * 4 + i][d];
        s[i][0] += a * b0; s[i][1] += a * b1;
      }
    }
    float mnew[4], alpha[4], lt[4];
    #pragma unroll
    for (int i = 0; i < 4; i++) {
      int qg = m0 + ty * 4 + i;
      #pragma unroll
      for (int j = 0; j < 2; j++) {
        int kg = kt + tx * 2 + j;
        float v = s[i][j] / sq + kbias[tx * 2 + j];
        if (selfmask && kg < qg) v += NEGV;
        s[i][j] = v;
      }
      float mv = fmaxf(s[i][0], s[i][1]);
      #pragma unroll
      for (int off = 1; off < 16; off <<= 1) mv = fmaxf(mv, __shfl_xor(mv, off, 16));
      int r = ty * 4 + i;
      float mo = row_m[r];
      float mn = fmaxf(mo, mv);
      mnew[i] = mn;
      alpha[i] = expf(mo - mn);
      float p0 = expf(s[i][0] - mn), p1 = expf(s[i][1] - mn);
      Ps[r][tx * 2 + 0] = p0; Ps[r][tx * 2 + 1] = p1;
      float ls = p0 + p1;
      #pragma unroll
      for (int off = 1; off < 16; off <<= 1) ls += __shfl_xor(ls, off, 16);
      lt[i] = ls;
    }
    __syncthreads();
    if (tx == 0) {
      #pragma unroll
      for (int i = 0; i < 4; i++) {
        int r = ty * 4 + i;
        row_m[r] = mnew[i];
        row_l[r] = row_l[r] * alpha[i] + lt[i];
      }
    }
    #pragma unroll
    for (int i = 0; i < 4; i++)
      #pragma unroll
      for (int j = 0; j < 6; j++) o[i][j] *= alpha[i];
    for (int k2 = 0; k2 < 32; k2++) {
      float vv[6];
      #pragma unroll
      for (int j = 0; j < 6; j++) vv[j] = Vs[k2][tx * 6 + j];
      #pragma unroll
      for (int i = 0; i < 4; i++) {
        float p = Ps[ty * 4 + i][k2];
        #pragma unroll
        for (int j = 0; j < 6; j++) o[i][j] += p * vv[j];
      }
    }
    __syncthreads();
  }
  #pragma unroll
  for (int i = 0; i < 4; i++) {
    int r = ty * 4 + i;
    float inv = 1.0f / row_l[r];
    float* orow = attO + (size_t)(b * NS + m0 + r) * ND + hh * NDH + tx * 6;
    #pragma unroll
    for (int j = 0; j < 6; j++) orow[j] = o[i][j] * inv;
  }
}

// ---------------- LayerNorm(res + x) -> dst ----------------
__global__ __launch_bounds__(256) void k_ln(
    const float* res, const float* x,
    const void* __restrict__ g, const void* __restrict__ bb, u64 goff,
    float* dst, const int* __restrict__ flag) {
  __shared__ float sred[256];
  int r = blockIdx.x, t = threadIdx.x;
  int isbf = *flag;
  const float* rr = res + (size_t)r * ND;
  const float* xr = x + (size_t)r * ND;
  float v0 = rr[t] + xr[t];
  float v1 = rr[t + 256] + xr[t + 256];
  float v2 = rr[t + 512] + xr[t + 512];
  float S = blockReduceSum256(v0 + v1 + v2, sred);
  float m = S / (float)ND;
  float d0 = v0 - m, d1 = v1 - m, d2 = v2 - m;
  float Q = blockReduceSum256(d0 * d0 + d1 * d1 + d2 * d2, sred);
  float inv = 1.0f / sqrtf(Q / (float)ND + 1e-5f);
  float* o = dst + (size_t)r * ND;
  o[t]       = d0 * inv * ldv(g, goff + t, isbf)       + ldv(bb, goff + t, isbf);
  o[t + 256] = d1 * inv * ldv(g, goff + t + 256, isbf) + ldv(bb, goff + t + 256, isbf);
  o[t + 512] = d2 * inv * ldv(g, goff + t + 512, isbf) + ldv(bb, goff + t + 512, isbf);
}

// ---------------------------------------------------------------------------
extern "C" void kernel_launch(void* const* d_in, const int* in_sizes, int n_in,
                              void* d_out, int out_size, void* d_ws, size_t ws_size,
                              hipStream_t stream) {
  const void* x        = d_in[0];
  const void* cb       = d_in[1];
  const void* sa_in_w  = d_in[2];
  const void* sa_in_b  = d_in[3];
  const void* sa_out_w = d_in[4];
  const void* sa_out_b = d_in[5];
  const void* ca_in_w  = d_in[6];
  const void* ca_in_b  = d_in[7];
  const void* ca_out_w = d_in[8];
  const void* ca_out_b = d_in[9];
  const void* ln1_g = d_in[10]; const void* ln1_b = d_in[11];
  const void* ln2_g = d_in[12]; const void* ln2_b = d_in[13];
  const void* ln3_g = d_in[14]; const void* ln3_b = d_in[15];
  const void* ff_w1 = d_in[16]; const void* ff_b1 = d_in[17];
  const void* ff_w2 = d_in[18]; const void* ff_b2 = d_in[19];
  const void* out_w = d_in[20]; const void* out_b = d_in[21];

  const size_t ZSZ = (size_t)NTOK * ND;
  float* ws   = (float*)d_ws;
  float* z    = ws;
  float* h    = z + ZSZ;
  float* qkv  = h + ZSZ;
  float* big  = qkv + 3 * ZSZ;
  float* tmp  = big + ZSZ;
  float* xn2  = tmp + ZSZ;
  float* cn2  = xn2 + NTOK;
  int*   padf = (int*)(cn2 + NK);
  int*   cand = padf + NTOK;
  int*   dflag = cand + (size_t)NTOK * 16;
  float* cbf  = big;
  float* attO = big;
  float* ff1  = qkv;

  // VQ scratch lives in the (currently dead) qkv region:
  // xhi/xlo (bf16 hi/lo planes of z), cbh (bf16 codebook), candv/candi.
  u16*   xhi   = (u16*)qkv;
  u16*   xlo   = xhi + ZSZ;
  u16*   cbh   = xlo + ZSZ;
  float* candv = (float*)(cbh + (size_t)NK * ND);
  int*   candi = (int*)(candv + (size_t)NTOK * 64);

  dim3 blk(256);

  k_detect   <<<1, 64, 0, stream>>>(x, dflag);
  k_pad_z    <<<NTOK, 256, 0, stream>>>(x, z, xn2, padf, xhi, xlo, dflag);
  k_cb       <<<NK,   256, 0, stream>>>(cb, cbf, cn2, cbh, dflag);
  k_vq_score <<<dim3(NTOK / 32, VQ_SPLIT), 256, 0, stream>>>(xhi, xlo, cbh, cn2, dflag, candv, candi);
  k_vq_merge <<<NTOK / 256, 256, 0, stream>>>(candv, candi, cand);
  k_vq_choose<<<NTOK, 64, 0, stream>>>(z, cbf, cand, h);

  const u64 WQKV = (u64)3 * ND * ND, WO = (u64)ND * ND;
  const u64 WF1 = (u64)NF * ND, WF2 = (u64)ND * NF;

  for (int l = 0; l < NL; l++) {
    // ---- self-attention ----
    k_gemm_nt<<<dim3(3 * ND / 64, NTOK / 64), blk, 0, stream>>>(
        h, sa_in_w, (u64)l * WQKV, sa_in_b, (u64)l * 3 * ND,
        qkv, NTOK, 3 * ND, ND, ND, ND, 3 * ND, 0, 0, dflag);
    k_flash<<<dim3(NS / 64, NB * NH), blk, 0, stream>>>(qkv, padf, attO, 1);
    k_gemm_nt<<<dim3(ND / 64, NTOK / 64), blk, 0, stream>>>(
        attO, sa_out_w, (u64)l * WO, sa_out_b, (u64)l * ND,
        tmp, NTOK, ND, ND, ND, ND, ND, 0, 0, dflag);
    k_ln<<<NTOK, 256, 0, stream>>>(h, tmp, ln1_g, ln1_b, (u64)l * ND, h, dflag);

    // ---- cross-attention: Q from h, K/V from mem (= z_e) ----
    k_gemm_nt<<<dim3(ND / 64, NTOK / 64), blk, 0, stream>>>(
        h, ca_in_w, (u64)l * WQKV, ca_in_b, (u64)l * 3 * ND,
        qkv, NTOK, ND, ND, ND, ND, 3 * ND, 0, 0, dflag);
    k_gemm_nt<<<dim3(2 * ND / 64, NTOK / 64), blk, 0, stream>>>(
        z, ca_in_w, (u64)l * WQKV + (u64)ND * ND, ca_in_b, (u64)l * 3 * ND + ND,
        qkv + ND, NTOK, 2 * ND, ND, ND, ND, 3 * ND, 0, 0, dflag);
    k_flash<<<dim3(NS / 64, NB * NH), blk, 0, stream>>>(qkv, padf, attO, 0);
    k_gemm_nt<<<dim3(ND / 64, NTOK / 64), blk, 0, stream>>>(
        attO, ca_out_w, (u64)l * WO, ca_out_b, (u64)l * ND,
        tmp, NTOK, ND, ND, ND, ND, ND, 0, 0, dflag);
    k_ln<<<NTOK, 256, 0, stream>>>(h, tmp, ln2_g, ln2_b, (u64)l * ND, h, dflag);

    // ---- feed-forward (ff1 aliases qkv, dead here) ----
    k_gemm_nt<<<dim3(NF / 64, NTOK / 64), blk, 0, stream>>>(
        h, ff_w1, (u64)l * WF1, ff_b1, (u64)l * NF,
        ff1, NTOK, NF, ND, ND, ND, NF, 1, 0, dflag);
    k_gemm_nt<<<dim3(ND / 64, NTOK / 64), blk, 0, stream>>>(
        ff1, ff_w2, (u64)l * WF2, ff_b2, (u64)l * ND,
        tmp, NTOK, ND, NF, NF, NF, ND, 0, 0, dflag);
    k_ln<<<NTOK, 256, 0, stream>>>(h, tmp, ln3_g, ln3_b, (u64)l * ND, h, dflag);
  }

  // ---- final projection -> output in input dtype ----
  k_gemm_nt<<<dim3(ND / 64, NTOK / 64), blk, 0, stream>>>(
      h, out_w, 0, out_b, 0, d_out, NTOK, ND, ND, ND, ND, ND, 0, 1, dflag);
}

// Round 4
// 10650.862 us; speedup vs baseline: 2.0173x; 1.6044x over previous
//
#include <hip/hip_runtime.h>
#include <math.h>

// ---------------------------------------------------------------------------
// Model_49675591746044: VQ + 6-layer post-LN transformer decoder.
// Round 8: decoder GEMMs -> bf16 MFMA (k_gemm_mfma, 128x128 tile, BK=32,
// global_load_lds with WAVE-UNIFORM dests via readfirstlane). A-operands are
// hi/lo bf16 planes produced by the upstream kernels (pad_z/choose/ln/flash/
// ff1-epilogue); products use ah*b + al*b (fp32-equivalent, weights exact in
// bf16 mode). fp32-input fallback: in-kernel B conversion + 3-MFMA path.
// VQ pipeline carried unchanged from the round-7 passing kernel.
// ---------------------------------------------------------------------------

#define THREEFRY_PARTITIONABLE 1

typedef unsigned short u16;
typedef unsigned int   u32;
typedef unsigned long long u64;

typedef short bf16x8 __attribute__((ext_vector_type(8)));
typedef float f32x4  __attribute__((ext_vector_type(4)));
typedef u16   u16x8  __attribute__((ext_vector_type(8)));

constexpr int NB  = 16;
constexpr int NS  = 512;
constexpr int ND  = 768;
constexpr int NK  = 8192;
constexpr int NH  = 8;
constexpr int NL  = 6;
constexpr int NF  = 2048;
constexpr int NTOK = NB * NS;   // 8192
constexpr int NDH  = ND / NH;   // 96
#define NEGV (-1e9f)

// VQ MFMA kernel geometry
constexpr int VQ_SPLIT = 4;
constexpr int VQ_CPS   = NK / VQ_SPLIT;
constexpr int VQ_TILES = VQ_CPS / 128;

// LDS byte offsets for k_vq_score (rows padded 64->72 elems = 144 B)
constexpr int L_ALO = 4608;
constexpr int L_B   = 9216;
constexpr int L_SC  = 27648;
constexpr int L_TOT = 44032;

// LDS byte offsets for k_gemm_mfma (rows of 32 bf16 = 64 B, 128 rows/plane)
constexpr int GAH = 0;
constexpr int GAL = 8192;
constexpr int GBH = 16384;
constexpr int GBL = 24576;
constexpr int GTOT = 32768 + 8192;   // 40960

__device__ __forceinline__ float b2f(u16 u) { return __uint_as_float(((u32)u) << 16); }
__device__ __forceinline__ u16 f2b(float f) {
  u32 u = __float_as_uint(f);
  u32 r = (u + 0x7FFFu + ((u >> 16) & 1u)) >> 16;
  return (u16)r;
}
__device__ __forceinline__ float ldv(const void* p, size_t i, int isbf) {
  return isbf ? b2f(((const u16*)p)[i]) : ((const float*)p)[i];
}

// ---------------- dtype detection ----------------
__global__ void k_detect(const void* x, int* flag) {
  if (threadIdx.x == 0 && blockIdx.x == 0) {
    const u16* p = (const u16*)x;
    int wild = 0;
    for (int i = 0; i < 1024; i++) {
      u16 u = p[i];
      u32 e = (u >> 7) & 0xFF;
      if (!(u == 0 || u == 0x8000u || (e >= 100 && e <= 134))) wild++;
    }
    *flag = (wild < 64) ? 1 : 0;   // 1 = bf16 inputs
  }
}

// ---------------- reductions (blockDim.x == 256) ----------------
__device__ __forceinline__ float blockReduceSum256(float v, float* s) {
  int t = threadIdx.x;
  s[t] = v; __syncthreads();
  #pragma unroll
  for (int off = 128; off > 0; off >>= 1) {
    if (t < off) s[t] += s[t + off];
    __syncthreads();
  }
  float r = s[0]; __syncthreads();
  return r;
}

// ---------------- pad mask + z_e (fp32) + hi/lo bf16 planes ----------------
__global__ __launch_bounds__(256) void k_pad_z(
    const void* __restrict__ x, float* __restrict__ z,
    float* __restrict__ xn2, int* __restrict__ padf,
    u16* __restrict__ zh, u16* __restrict__ zl,
    const int* __restrict__ flag) {
  __shared__ float sred[256];
  int r = blockIdx.x, t = threadIdx.x;
  int isbf = *flag;
  size_t base = (size_t)r * ND;
  float a0 = ldv(x, base + t, isbf);
  float a1 = ldv(x, base + t + 256, isbf);
  float a2 = ldv(x, base + t + 512, isbf);
  float ss = blockReduceSum256(a0 * a0 + a1 * a1 + a2 * a2, sred);
  int pad = (sqrtf(ss) <= 1e-6f) ? 1 : 0;
  if (pad) { a0 = 0.f; a1 = 0.f; a2 = 0.f; }
  float* zr = z + base;
  zr[t] = a0; zr[t + 256] = a1; zr[t + 512] = a2;
  u16 h0 = f2b(a0), h1 = f2b(a1), h2 = f2b(a2);
  zh[base + t] = h0; zh[base + t + 256] = h1; zh[base + t + 512] = h2;
  zl[base + t]       = f2b(a0 - b2f(h0));
  zl[base + t + 256] = f2b(a1 - b2f(h1));
  zl[base + t + 512] = f2b(a2 - b2f(h2));
  if (t == 0) { xn2[r] = pad ? 0.f : ss; padf[r] = pad; }
}

// ---------------- codebook -> fp32 copy + bf16 copy + |c|^2 ----------------
__global__ __launch_bounds__(256) void k_cb(
    const void* __restrict__ cb, float* __restrict__ cbf, float* __restrict__ cn2,
    u16* __restrict__ cbh, const int* __restrict__ flag) {
  __shared__ float sred[256];
  int r = blockIdx.x, t = threadIdx.x;
  int isbf = *flag;
  size_t base = (size_t)r * ND;
  float a0 = ldv(cb, base + t, isbf);
  float a1 = ldv(cb, base + t + 256, isbf);
  float a2 = ldv(cb, base + t + 512, isbf);
  float* o = cbf + base;
  o[t] = a0; o[t + 256] = a1; o[t + 512] = a2;
  cbh[base + t] = f2b(a0); cbh[base + t + 256] = f2b(a1); cbh[base + t + 512] = f2b(a2);
  float ss = blockReduceSum256(a0 * a0 + a1 * a1 + a2 * a2, sred);
  if (t == 0) cn2[r] = ss;
}

// ---------------- top-16 insertion (running worst at wslot) ----------------
#define VQ_INSERT(dt, kk)                                                    \
  if ((dt) < wv) {                                                           \
    _Pragma("unroll")                                                        \
    for (int j = 0; j < 16; j++)                                             \
      if (j == wslot) { bestv[j] = (dt); besti[j] = (kk); }                  \
    wv = bestv[0]; wslot = 0;                                                \
    _Pragma("unroll")                                                        \
    for (int j = 1; j < 16; j++)                                             \
      if (bestv[j] > wv) { wv = bestv[j]; wslot = j; }                       \
  }

// ---------------- VQ scores via bf16 MFMA, fused top-16 --------------------
__global__ __launch_bounds__(256) void k_vq_score(
    const u16* __restrict__ xhi, const u16* __restrict__ xlo,
    const u16* __restrict__ cbh, const float* __restrict__ cn2,
    const int* __restrict__ flag,
    float* __restrict__ candv, int* __restrict__ candi) {
  __shared__ __align__(16) char lds[L_TOT];
  const int t = threadIdx.x;
  const int l = t & 63, w = t >> 6;
  const int rowbase = blockIdx.x * 32;
  const int split = blockIdx.y;
  const int dolo = (*flag) == 0;

  const int arow = t >> 3, aslot = t & 7;
  const size_t srcA = (size_t)(rowbase + arow) * ND + aslot * 8;
  const int dstA = arow * 144 + aslot * 16;
  const int c0 = (t >> 3), c1 = 32 + c0, c2 = 64 + c0, c3 = 96 + c0;
  const int dstB0 = L_B + c0 * 144 + aslot * 16;
  const int dstB1 = L_B + c1 * 144 + aslot * 16;
  const int dstB2 = L_B + c2 * 144 + aslot * 16;
  const int dstB3 = L_B + c3 * 144 + aslot * 16;

  int aoff[2][2], boff[2][2];
  #pragma unroll
  for (int mi = 0; mi < 2; mi++)
    #pragma unroll
    for (int ks = 0; ks < 2; ks++)
      aoff[mi][ks] = (mi * 16 + (l & 15)) * 144 + (ks * 4 + (l >> 4)) * 16;
  #pragma unroll
  for (int ni = 0; ni < 2; ni++)
    #pragma unroll
    for (int ks = 0; ks < 2; ks++)
      boff[ni][ks] = L_B + (w * 32 + ni * 16 + (l & 15)) * 144 + (ks * 4 + (l >> 4)) * 16;

  float* scores = (float*)(lds + L_SC);

  float bestv[16]; int besti[16];
  #pragma unroll
  for (int j = 0; j < 16; j++) { bestv[j] = 3.4e38f; besti[j] = 0; }
  float wv = 3.4e38f; int wslot = 0;

  for (int tile = 0; tile < VQ_TILES; tile++) {
    const int codebase = split * VQ_CPS + tile * 128;
    f32x4 acc[2][2];
    #pragma unroll
    for (int ni = 0; ni < 2; ni++) {
      float cv = -0.5f * cn2[codebase + w * 32 + ni * 16 + (l & 15)];
      f32x4 ini = {cv, cv, cv, cv};
      acc[0][ni] = ini; acc[1][ni] = ini;
    }
    const u16* pB0 = cbh + (size_t)(codebase + c0) * ND + aslot * 8;
    const u16* pB1 = cbh + (size_t)(codebase + c1) * ND + aslot * 8;
    const u16* pB2 = cbh + (size_t)(codebase + c2) * ND + aslot * 8;
    const u16* pB3 = cbh + (size_t)(codebase + c3) * ND + aslot * 8;

    for (int kc = 0; kc < 12; kc++) {
      const int ko = kc * 64;
      u16x8 vah = *(const u16x8*)(xhi + srcA + ko);
      u16x8 valr = {};
      if (dolo) valr = *(const u16x8*)(xlo + srcA + ko);
      u16x8 vb0 = *(const u16x8*)(pB0 + ko);
      u16x8 vb1 = *(const u16x8*)(pB1 + ko);
      u16x8 vb2 = *(const u16x8*)(pB2 + ko);
      u16x8 vb3 = *(const u16x8*)(pB3 + ko);
      __syncthreads();
      *(u16x8*)(lds + dstA) = vah;
      if (dolo) *(u16x8*)(lds + L_ALO + dstA) = valr;
      *(u16x8*)(lds + dstB0) = vb0;
      *(u16x8*)(lds + dstB1) = vb1;
      *(u16x8*)(lds + dstB2) = vb2;
      *(u16x8*)(lds + dstB3) = vb3;
      __syncthreads();
      #pragma unroll
      for (int ks = 0; ks < 2; ks++) {
        bf16x8 b0  = *(const bf16x8*)(lds + boff[0][ks]);
        bf16x8 b1  = *(const bf16x8*)(lds + boff[1][ks]);
        bf16x8 ah0 = *(const bf16x8*)(lds + aoff[0][ks]);
        bf16x8 ah1 = *(const bf16x8*)(lds + aoff[1][ks]);
        acc[0][0] = __builtin_amdgcn_mfma_f32_16x16x32_bf16(ah0, b0, acc[0][0], 0, 0, 0);
        acc[1][0] = __builtin_amdgcn_mfma_f32_16x16x32_bf16(ah1, b0, acc[1][0], 0, 0, 0);
        acc[0][1] = __builtin_amdgcn_mfma_f32_16x16x32_bf16(ah0, b1, acc[0][1], 0, 0, 0);
        acc[1][1] = __builtin_amdgcn_mfma_f32_16x16x32_bf16(ah1, b1, acc[1][1], 0, 0, 0);
        if (dolo) {
          bf16x8 al0 = *(const bf16x8*)(lds + L_ALO + aoff[0][ks]);
          bf16x8 al1 = *(const bf16x8*)(lds + L_ALO + aoff[1][ks]);
          acc[0][0] = __builtin_amdgcn_mfma_f32_16x16x32_bf16(al0, b0, acc[0][0], 0, 0, 0);
          acc[1][0] = __builtin_amdgcn_mfma_f32_16x16x32_bf16(al1, b0, acc[1][0], 0, 0, 0);
          acc[0][1] = __builtin_amdgcn_mfma_f32_16x16x32_bf16(al0, b1, acc[0][1], 0, 0, 0);
          acc[1][1] = __builtin_amdgcn_mfma_f32_16x16x32_bf16(al1, b1, acc[1][1], 0, 0, 0);
        }
      }
    }
    #pragma unroll
    for (int mi = 0; mi < 2; mi++)
      #pragma unroll
      for (int ni = 0; ni < 2; ni++)
        #pragma unroll
        for (int r = 0; r < 4; r++) {
          int srow = mi * 16 + (l >> 4) * 4 + r;
          int scol = w * 32 + ni * 16 + (l & 15);
          scores[srow * 128 + scol] = -2.0f * acc[mi][ni][r];
        }
    __syncthreads();
    {
      int irow = t >> 3, isub = t & 7;
      const float* srow = scores + irow * 128;
      #pragma unroll
      for (int i = 0; i < 16; i++) {
        int c = isub + i * 8;
        float key = srow[c];
        int gk = codebase + c;
        VQ_INSERT(key, gk)
      }
    }
    __syncthreads();
  }

  float* svals = (float*)lds;
  int*   sidx  = (int*)(lds + 16384);
  {
    int irow = t >> 3, isub = t & 7;
    #pragma unroll
    for (int j = 0; j < 16; j++) {
      svals[irow * 128 + isub * 16 + j] = bestv[j];
      sidx [irow * 128 + isub * 16 + j] = besti[j];
    }
  }
  __syncthreads();
  if (t < 32) {
    float bv[16]; int bi[16]; float w2 = 3.4e38f; int ws2 = 0;
    #pragma unroll
    for (int j = 0; j < 16; j++) { bv[j] = 3.4e38f; bi[j] = 0; }
    const float* sv = svals + t * 128;
    const int*   si = sidx  + t * 128;
    for (int i = 0; i < 128; i++) {
      float dv = sv[i];
      if (dv < w2) {
        int ii = si[i];
        #pragma unroll
        for (int j = 0; j < 16; j++)
          if (j == ws2) { bv[j] = dv; bi[j] = ii; }
        w2 = bv[0]; ws2 = 0;
        #pragma unroll
        for (int j = 1; j < 16; j++)
          if (bv[j] > w2) { w2 = bv[j]; ws2 = j; }
      }
    }
    float* ov = candv + ((size_t)(rowbase + t) * VQ_SPLIT + split) * 16;
    int*   oi = candi + ((size_t)(rowbase + t) * VQ_SPLIT + split) * 16;
    #pragma unroll
    for (int j = 0; j < 16; j++) { ov[j] = bv[j]; oi[j] = bi[j]; }
  }
}

// ---------------- merge across splits: 64 candidates -> 16 ----------------
__global__ __launch_bounds__(256) void k_vq_merge(
    const float* __restrict__ candv, const int* __restrict__ candi,
    int* __restrict__ cand) {
  int row = blockIdx.x * 256 + threadIdx.x;
  float bestv[16]; int besti[16];
  #pragma unroll
  for (int j = 0; j < 16; j++) { bestv[j] = 3.4e38f; besti[j] = 0; }
  float wv = 3.4e38f; int wslot = 0;
  const float* sv = candv + (size_t)row * 64;
  const int*   si = candi + (size_t)row * 64;
  for (int i = 0; i < 64; i++) {
    float dv = sv[i]; int ii = si[i];
    VQ_INSERT(dv, ii)
  }
  int* o = cand + (size_t)row * 16;
  #pragma unroll
  for (int j = 0; j < 16; j++) o[j] = besti[j];
}

// ---------------- threefry2x32, key (0, 42) ----------------
__device__ __forceinline__ void threefry2x32_042(u32 c0, u32 c1, u32& o0, u32& o1) {
  const u32 K0 = 0u, K1 = 42u, K2 = 0u ^ 42u ^ 0x1BD11BDAu;
  u32 x0 = c0 + K0, x1 = c1 + K1;
  #define TF_R(r) { x0 += x1; x1 = (x1 << (r)) | (x1 >> (32 - (r))); x1 ^= x0; }
  TF_R(13) TF_R(15) TF_R(26) TF_R(6)   x0 += K1; x1 += K2 + 1u;
  TF_R(17) TF_R(29) TF_R(16) TF_R(24)  x0 += K2; x1 += K0 + 2u;
  TF_R(13) TF_R(15) TF_R(26) TF_R(6)   x0 += K0; x1 += K1 + 3u;
  TF_R(17) TF_R(29) TF_R(16) TF_R(24)  x0 += K1; x1 += K2 + 4u;
  TF_R(13) TF_R(15) TF_R(26) TF_R(6)   x0 += K2; x1 += K0 + 5u;
  #undef TF_R
  o0 = x0; o1 = x1;
}

__device__ __forceinline__ u32 jax_bits(u32 e) {
  u32 b0, b1;
#if THREEFRY_PARTITIONABLE
  threefry2x32_042(0u, e, b0, b1);
  return b0 ^ b1;
#else
  const u32 HALF = (u32)(NTOK * 10 / 2);
  if (e < HALF) { threefry2x32_042(e, e + HALF, b0, b1); return b0; }
  else          { threefry2x32_042(e - HALF, e, b0, b1); return b1; }
#endif
}

// ---------------- VQ refine (fp64) + gumbel choose + write quantized --------
__global__ __launch_bounds__(64) void k_vq_choose(
    const float* __restrict__ z, const float* __restrict__ cbf,
    const int* __restrict__ cand, float* __restrict__ h,
    u16* __restrict__ oh, u16* __restrict__ ol) {
  __shared__ double s_xc[64], s_c2[64];
  __shared__ double dvals[16]; __shared__ int didx[16];
  __shared__ int s_enc;
  __shared__ double s_x2v;
  int r = blockIdx.x, t = threadIdx.x;
  int c = t >> 2, p = t & 3;
  int idx = cand[(size_t)r * 16 + c];
  const float* xr = z + (size_t)r * ND;
  const float* cr = cbf + (size_t)idx * ND;
  double xc = 0.0, c2 = 0.0;
  for (int d = p * 192; d < p * 192 + 192; d++) {
    double xv = (double)xr[d], cv = (double)cr[d];
    xc += xv * cv; c2 += cv * cv;
  }
  s_xc[t] = xc; s_c2[t] = c2;
  __syncthreads();
  if (t == 0) {
    double sx2 = 0;
    for (int d = 0; d < ND; d++) { double xv = (double)xr[d]; sx2 += xv * xv; }
    s_x2v = sx2;
  }
  __syncthreads();
  if (t < 16) {
    double sxc = 0, sc2 = 0;
    for (int pp = 0; pp < 4; pp++) { sxc += s_xc[t * 4 + pp]; sc2 += s_c2[t * 4 + pp]; }
    dvals[t] = s_x2v + sc2 - 2.0 * sxc;
    didx[t]  = cand[(size_t)r * 16 + t];
  }
  __syncthreads();
  if (t == 0) {
    double dv[16]; int di[16];
    for (int j = 0; j < 16; j++) { dv[j] = dvals[j]; di[j] = didx[j]; }
    for (int a = 1; a < 16; a++) {
      double vv = dv[a]; int ii = di[a]; int b = a;
      while (b > 0 && (dv[b-1] > vv || (dv[b-1] == vv && di[b-1] > ii))) {
        dv[b] = dv[b-1]; di[b] = di[b-1]; b--;
      }
      dv[b] = vv; di[b] = ii;
    }
    double bestsc = -1e300; int bestj = 0;
    for (int j = 0; j < 10; j++) {
      u32 e = (u32)(r * 10 + j);
      u32 bits = jax_bits(e);
      u32 fb = (bits >> 9) | 0x3f800000u;
      float uf = __uint_as_float(fb) - 1.0f;
      float vf = uf + 1e-10f;
      vf = fmaxf(1e-10f, vf);
      double g = -log(-log((double)vf));
      double sc = -dv[j] + g;
      if (sc > bestsc) { bestsc = sc; bestj = j; }
    }
    s_enc = di[bestj];
  }
  __syncthreads();
  int enc = s_enc;
  const float* qv = cbf + (size_t)enc * ND;
  float* hr = h + (size_t)r * ND;
  size_t base = (size_t)r * ND;
  for (int d = t; d < ND; d += 64) {
    float v = qv[d];
    hr[d] = v;
    u16 hv = f2b(v);
    oh[base + d] = hv;
    ol[base + d] = f2b(v - b2f(hv));
  }
}

// ---------------- MFMA GEMM: C = A[M,K] * B[N,K]^T + bias -------------------
// A given as hi/lo bf16 planes [M][lda]; B = weights (bf16 u16 direct, or fp32
// converted in-kernel). 128x128 tile, BK=32, 256 thr (2x2 waves of 64x64).
// outMode: 0 = fp32 Cv; 1 = input dtype Cv; 2 = hi/lo planes Chi/Clo.
__global__ __launch_bounds__(256) void k_gemm_mfma(
    const u16* __restrict__ Ah, const u16* __restrict__ Al, int lda,
    const void* __restrict__ Bw, u64 boffx, int ldb,
    const void* __restrict__ bias, u64 bioff,
    void* __restrict__ Cv, u16* __restrict__ Chi, u16* __restrict__ Clo, int ldc,
    int Kd, int relu, int outMode, const int* __restrict__ flag) {
  __shared__ __align__(16) char lds[GTOT];
  const int t = threadIdx.x, l = t & 63, w = t >> 6;
  const int wm = w >> 1, wn = w & 1;
  const int m0 = blockIdx.y * 128, n0 = blockIdx.x * 128;
  const int isbf = *flag;
  const u16*   b16 = (const u16*)Bw + boffx;
  const float* b32 = (const float*)Bw + boffx;

  // staging sources: chunk i = (w*2+c)*64 + l -> row i>>2, 16B-slot i&3
  const int i0 = (w * 2 + 0) * 64 + l, i1 = (w * 2 + 1) * 64 + l;
  const u16* sAh0 = Ah + (size_t)(m0 + (i0 >> 2)) * lda + (i0 & 3) * 8;
  const u16* sAh1 = Ah + (size_t)(m0 + (i1 >> 2)) * lda + (i1 & 3) * 8;
  const u16* sAl0 = Al + (size_t)(m0 + (i0 >> 2)) * lda + (i0 & 3) * 8;
  const u16* sAl1 = Al + (size_t)(m0 + (i1 >> 2)) * lda + (i1 & 3) * 8;
  const u16* sB0  = b16 + (size_t)(n0 + (i0 >> 2)) * ldb + (i0 & 3) * 8;
  const u16* sB1  = b16 + (size_t)(n0 + (i1 >> 2)) * ldb + (i1 & 3) * 8;
  // wave-uniform LDS dest offsets (forced to SGPR)
  const int wo = __builtin_amdgcn_readfirstlane(w * 2048);

  // fp32-B fallback (uniform branch): thread t -> row t>>1, k-half (t&1)*16
  const int brow = t >> 1, bko = (t & 1) * 16;
  const float* sBf = b32 + (size_t)(n0 + brow) * ldb + bko;
  const int dBw = brow * 64 + bko * 2;

  // fragment read offsets
  int aro[4], bro[4];
  #pragma unroll
  for (int mi = 0; mi < 4; mi++)
    aro[mi] = (wm * 64 + mi * 16 + (l & 15)) * 64 + (l >> 4) * 16;
  #pragma unroll
  for (int ni = 0; ni < 4; ni++)
    bro[ni] = (wn * 64 + ni * 16 + (l & 15)) * 64 + (l >> 4) * 16;

  // acc init = bias (C/D col = l&15)
  f32x4 acc[4][4];
  #pragma unroll
  for (int ni = 0; ni < 4; ni++) {
    float bv = ldv(bias, bioff + n0 + wn * 64 + ni * 16 + (l & 15), isbf);
    f32x4 ini = {bv, bv, bv, bv};
    #pragma unroll
    for (int mi = 0; mi < 4; mi++) acc[mi][ni] = ini;
  }

  const int nkt = Kd >> 5;
  for (int kt = 0; kt < nkt; kt++) {
    float bf[16];
    if (!isbf) {
      #pragma unroll
      for (int q = 0; q < 4; q++) {
        float4 fv = *(const float4*)(sBf + q * 4);
        bf[q * 4 + 0] = fv.x; bf[q * 4 + 1] = fv.y;
        bf[q * 4 + 2] = fv.z; bf[q * 4 + 3] = fv.w;
      }
    }
    __syncthreads();    // previous compute done reading LDS
    __builtin_amdgcn_global_load_lds((const __attribute__((address_space(1))) unsigned int*)sAh0,
        (__attribute__((address_space(3))) unsigned int*)(lds + GAH + wo), 16, 0, 0);
    __builtin_amdgcn_global_load_lds((const __attribute__((address_space(1))) unsigned int*)sAh1,
        (__attribute__((address_space(3))) unsigned int*)(lds + GAH + wo + 1024), 16, 0, 0);
    __builtin_amdgcn_global_load_lds((const __attribute__((address_space(1))) unsigned int*)sAl0,
        (__attribute__((address_space(3))) unsigned int*)(lds + GAL + wo), 16, 0, 0);
    __builtin_amdgcn_global_load_lds((const __attribute__((address_space(1))) unsigned int*)sAl1,
        (__attribute__((address_space(3))) unsigned int*)(lds + GAL + wo + 1024), 16, 0, 0);
    if (isbf) {
      __builtin_amdgcn_global_load_lds((const __attribute__((address_space(1))) unsigned int*)sB0,
          (__attribute__((address_space(3))) unsigned int*)(lds + GBH + wo), 16, 0, 0);
      __builtin_amdgcn_global_load_lds((const __attribute__((address_space(1))) unsigned int*)sB1,
          (__attribute__((address_space(3))) unsigned int*)(lds + GBH + wo + 1024), 16, 0, 0);
    } else {
      u16x8 h0, h1, l0v, l1v;
      #pragma unroll
      for (int j = 0; j < 8; j++) {
        u16 hv = f2b(bf[j]);     h0[j] = (short)hv;  l0v[j] = (short)f2b(bf[j] - b2f(hv));
        u16 hw = f2b(bf[8 + j]); h1[j] = (short)hw;  l1v[j] = (short)f2b(bf[8 + j] - b2f(hw));
      }
      *(u16x8*)(lds + GBH + dBw)      = h0;
      *(u16x8*)(lds + GBH + dBw + 16) = h1;
      *(u16x8*)(lds + GBL + dBw)      = l0v;
      *(u16x8*)(lds + GBL + dBw + 16) = l1v;
    }
    __syncthreads();    // staging visible (vmcnt + lgkm drained by barrier)

    bf16x8 ah[4], al[4];
    #pragma unroll
    for (int mi = 0; mi < 4; mi++) {
      ah[mi] = *(const bf16x8*)(lds + GAH + aro[mi]);
      al[mi] = *(const bf16x8*)(lds + GAL + aro[mi]);
    }
    #pragma unroll
    for (int ni = 0; ni < 4; ni++) {
      bf16x8 bh = *(const bf16x8*)(lds + GBH + bro[ni]);
      #pragma unroll
      for (int mi = 0; mi < 4; mi++)
        acc[mi][ni] = __builtin_amdgcn_mfma_f32_16x16x32_bf16(ah[mi], bh, acc[mi][ni], 0, 0, 0);
      #pragma unroll
      for (int mi = 0; mi < 4; mi++)
        acc[mi][ni] = __builtin_amdgcn_mfma_f32_16x16x32_bf16(al[mi], bh, acc[mi][ni], 0, 0, 0);
      if (!isbf) {
        bf16x8 bl = *(const bf16x8*)(lds + GBL + bro[ni]);
        #pragma unroll
        for (int mi = 0; mi < 4; mi++)
          acc[mi][ni] = __builtin_amdgcn_mfma_f32_16x16x32_bf16(ah[mi], bl, acc[mi][ni], 0, 0, 0);
      }
    }
    sAh0 += 32; sAh1 += 32; sAl0 += 32; sAl1 += 32;
    sB0 += 32; sB1 += 32; sBf += 32;
  }

  // epilogue: C/D layout col=l&15, row=(l>>4)*4+reg  [verified]
  #pragma unroll
  for (int mi = 0; mi < 4; mi++)
    #pragma unroll
    for (int ni = 0; ni < 4; ni++) {
      int col = n0 + wn * 64 + ni * 16 + (l & 15);
      #pragma unroll
      for (int r = 0; r < 4; r++) {
        int row = m0 + wm * 64 + mi * 16 + (l >> 4) * 4 + r;
        float v = acc[mi][ni][r];
        if (relu) v = fmaxf(v, 0.f);
        size_t ci = (size_t)row * ldc + col;
        if (outMode == 0) {
          ((float*)Cv)[ci] = v;
        } else if (outMode == 1) {
          if (isbf) ((u16*)Cv)[ci] = f2b(v);
          else      ((float*)Cv)[ci] = v;
        } else {
          u16 hv = f2b(v);
          Chi[ci] = hv;
          Clo[ci] = f2b(v - b2f(hv));
        }
      }
    }
}

// ---------------- flash attention -> hi/lo plane output ---------------------
__global__ __launch_bounds__(256) void k_flash(
    const float* __restrict__ qkv, const int* __restrict__ padf,
    u16* __restrict__ oh, u16* __restrict__ ol, int selfmask) {
  __shared__ float Qs[64][97];
  __shared__ float Ks[32][97];
  __shared__ float Vs[32][97];
  __shared__ float Ps[64][33];
  __shared__ float row_m[64], row_l[64], kbias[32];
  int zb = blockIdx.y; int b = zb >> 3, hh = zb & 7;
  int m0 = blockIdx.x * 64;
  int tid = threadIdx.x, tx = tid & 15, ty = tid >> 4;
  const float* Qb = qkv + (size_t)b * NS * (3 * ND) + hh * NDH;
  const float* Kb = Qb + ND;
  const float* Vb = Qb + 2 * ND;
  for (int e = tid; e < 64 * 96; e += 256) {
    int r = e / 96, c = e - r * 96;
    Qs[r][c] = Qb[(size_t)(m0 + r) * (3 * ND) + c];
  }
  if (tid < 64) { row_m[tid] = -3.0e38f; row_l[tid] = 0.f; }
  __syncthreads();
  float o[4][6];
  #pragma unroll
  for (int i = 0; i < 4; i++)
    #pragma unroll
    for (int j = 0; j < 6; j++) o[i][j] = 0.f;
  const float sq = sqrtf(96.0f);

  for (int kt = 0; kt < NS; kt += 32) {
    for (int e = tid; e < 32 * 96; e += 256) {
      int r = e / 96, c = e - r * 96;
      Ks[r][c] = Kb[(size_t)(kt + r) * (3 * ND) + c];
      Vs[r][c] = Vb[(size_t)(kt + r) * (3 * ND) + c];
    }
    if (tid < 32) kbias[tid] = padf[b * NS + kt + tid] ? NEGV : 0.f;
    __syncthreads();

    float s[4][2];
    #pragma unroll
    for (int i = 0; i < 4; i++) { s[i][0] = 0.f; s[i][1] = 0.f; }
    for (int d = 0; d < 96; d++) {
      float b0 = Ks[tx * 2 + 0][d], b1 = Ks[tx * 2 + 1][d];
      #pragma unroll
      for (int i = 0; i < 4; i++) {
        float a = Qs[ty * 4 + i][d];
        s[i][0] += a * b0; s[i][1] += a * b1;
      }
    }
    float mnew[4], alpha[4], lt[4];
    #pragma unroll
    for (int i = 0; i < 4; i++) {
      int qg = m0 + ty * 4 + i;
      #pragma unroll
      for (int j = 0; j < 2; j++) {
        int kg = kt + tx * 2 + j;
        float v = s[i][j] / sq + kbias[tx * 2 + j];
        if (selfmask && kg < qg) v += NEGV;
        s[i][j] = v;
      }
      float mv = fmaxf(s[i][0], s[i][1]);
      #pragma unroll
      for (int off = 1; off < 16; off <<= 1) mv = fmaxf(mv, __shfl_xor(mv, off, 16));
      int r = ty * 4 + i;
      float mo = row_m[r];
      float mn = fmaxf(mo, mv);
      mnew[i] = mn;
      alpha[i] = expf(mo - mn);
      float p0 = expf(s[i][0] - mn), p1 = expf(s[i][1] - mn);
      Ps[r][tx * 2 + 0] = p0; Ps[r][tx * 2 + 1] = p1;
      float ls = p0 + p1;
      #pragma unroll
      for (int off = 1; off < 16; off <<= 1) ls += __shfl_xor(ls, off, 16);
      lt[i] = ls;
    }
    __syncthreads();
    if (tx == 0) {
      #pragma unroll
      for (int i = 0; i < 4; i++) {
        int r = ty * 4 + i;
        row_m[r] = mnew[i];
        row_l[r] = row_l[r] * alpha[i] + lt[i];
      }
    }
    #pragma unroll
    for (int i = 0; i < 4; i++)
      #pragma unroll
      for (int j = 0; j < 6; j++) o[i][j] *= alpha[i];
    for (int k2 = 0; k2 < 32; k2++) {
      float vv[6];
      #pragma unroll
      for (int j = 0; j < 6; j++) vv[j] = Vs[k2][tx * 6 + j];
      #pragma unroll
      for (int i = 0; i < 4; i++) {
        float p = Ps[ty * 4 + i][k2];
        #pragma unroll
        for (int j = 0; j < 6; j++) o[i][j] += p * vv[j];
      }
    }
    __syncthreads();
  }
  #pragma unroll
  for (int i = 0; i < 4; i++) {
    int r = ty * 4 + i;
    float inv = 1.0f / row_l[r];
    size_t base = (size_t)(b * NS + m0 + r) * ND + hh * NDH + tx * 6;
    #pragma unroll
    for (int j = 0; j < 6; j++) {
      float val = o[i][j] * inv;
      u16 hv = f2b(val);
      oh[base + j] = hv;
      ol[base + j] = f2b(val - b2f(hv));
    }
  }
}

// ---------------- LayerNorm(res + x) -> dst + hi/lo planes ----------------
__global__ __launch_bounds__(256) void k_ln(
    const float* res, const float* x,
    const void* __restrict__ g, const void* __restrict__ bb, u64 goff,
    float* dst, u16* __restrict__ oh, u16* __restrict__ ol,
    const int* __restrict__ flag) {
  __shared__ float sred[256];
  int r = blockIdx.x, t = threadIdx.x;
  int isbf = *flag;
  size_t base = (size_t)r * ND;
  const float* rr = res + base;
  const float* xr = x + base;
  float v0 = rr[t] + xr[t];
  float v1 = rr[t + 256] + xr[t + 256];
  float v2 = rr[t + 512] + xr[t + 512];
  float S = blockReduceSum256(v0 + v1 + v2, sred);
  float m = S / (float)ND;
  float d0 = v0 - m, d1 = v1 - m, d2 = v2 - m;
  float Q = blockReduceSum256(d0 * d0 + d1 * d1 + d2 * d2, sred);
  float inv = 1.0f / sqrtf(Q / (float)ND + 1e-5f);
  float* o = dst + base;
  float y0 = d0 * inv * ldv(g, goff + t, isbf)       + ldv(bb, goff + t, isbf);
  float y1 = d1 * inv * ldv(g, goff + t + 256, isbf) + ldv(bb, goff + t + 256, isbf);
  float y2 = d2 * inv * ldv(g, goff + t + 512, isbf) + ldv(bb, goff + t + 512, isbf);
  o[t] = y0; o[t + 256] = y1; o[t + 512] = y2;
  u16 h0 = f2b(y0), h1 = f2b(y1), h2 = f2b(y2);
  oh[base + t] = h0; oh[base + t + 256] = h1; oh[base + t + 512] = h2;
  ol[base + t]       = f2b(y0 - b2f(h0));
  ol[base + t + 256] = f2b(y1 - b2f(h1));
  ol[base + t + 512] = f2b(y2 - b2f(h2));
}

// ---------------------------------------------------------------------------
extern "C" void kernel_launch(void* const* d_in, const int* in_sizes, int n_in,
                              void* d_out, int out_size, void* d_ws, size_t ws_size,
                              hipStream_t stream) {
  const void* x        = d_in[0];
  const void* cb       = d_in[1];
  const void* sa_in_w  = d_in[2];
  const void* sa_in_b  = d_in[3];
  const void* sa_out_w = d_in[4];
  const void* sa_out_b = d_in[5];
  const void* ca_in_w  = d_in[6];
  const void* ca_in_b  = d_in[7];
  const void* ca_out_w = d_in[8];
  const void* ca_out_b = d_in[9];
  const void* ln1_g = d_in[10]; const void* ln1_b = d_in[11];
  const void* ln2_g = d_in[12]; const void* ln2_b = d_in[13];
  const void* ln3_g = d_in[14]; const void* ln3_b = d_in[15];
  const void* ff_w1 = d_in[16]; const void* ff_b1 = d_in[17];
  const void* ff_w2 = d_in[18]; const void* ff_b2 = d_in[19];
  const void* out_w = d_in[20]; const void* out_b = d_in[21];

  const size_t ZSZ = (size_t)NTOK * ND;
  float* ws   = (float*)d_ws;
  float* z    = ws;
  float* h    = z + ZSZ;
  float* qkv  = h + ZSZ;          // 3 ZSZ (aliased: VQ scratch, then ff planes)
  float* big  = qkv + 3 * ZSZ;    // cbf during VQ
  float* tmp  = big + ZSZ;
  u16*   zplh = (u16*)(tmp + ZSZ);
  u16*   zpll = zplh + ZSZ;
  u16*   aplh = zpll + ZSZ;
  u16*   apll = aplh + ZSZ;
  float* xn2  = (float*)(apll + ZSZ);   // = ws + 9*ZSZ floats
  float* cn2  = xn2 + NTOK;
  int*   padf = (int*)(cn2 + NK);
  int*   cand = padf + NTOK;
  int*   dflag = cand + (size_t)NTOK * 16;
  float* cbf  = big;
  // VQ scratch inside qkv region (dead until decoder starts)
  u16*   cbh   = (u16*)qkv;
  float* candv = (float*)(cbh + (size_t)NK * ND);
  int*   candi = (int*)(candv + (size_t)NTOK * 64);
  // ff1 output planes inside qkv region (qkv dead during the ff block)
  u16*   fplh = (u16*)qkv;
  u16*   fpll = fplh + (size_t)NTOK * NF;

  dim3 blk(256);

  k_detect   <<<1, 64, 0, stream>>>(x, dflag);
  k_pad_z    <<<NTOK, 256, 0, stream>>>(x, z, xn2, padf, zplh, zpll, dflag);
  k_cb       <<<NK,   256, 0, stream>>>(cb, cbf, cn2, cbh, dflag);
  k_vq_score <<<dim3(NTOK / 32, VQ_SPLIT), 256, 0, stream>>>(zplh, zpll, cbh, cn2, dflag, candv, candi);
  k_vq_merge <<<NTOK / 256, 256, 0, stream>>>(candv, candi, cand);
  k_vq_choose<<<NTOK, 64, 0, stream>>>(z, cbf, cand, h, aplh, apll);

  const u64 WQKV = (u64)3 * ND * ND, WO = (u64)ND * ND;
  const u64 WF1 = (u64)NF * ND, WF2 = (u64)ND * NF;
  const dim3 gM64(64, 1, 1);

  for (int l = 0; l < NL; l++) {
    // ---- self-attention ----
    k_gemm_mfma<<<dim3(3 * ND / 128, NTOK / 128), blk, 0, stream>>>(
        aplh, apll, ND, sa_in_w, (u64)l * WQKV, ND, sa_in_b, (u64)l * 3 * ND,
        qkv, nullptr, nullptr, 3 * ND, ND, 0, 0, dflag);
    k_flash<<<dim3(NS / 64, NB * NH), blk, 0, stream>>>(qkv, padf, aplh, apll, 1);
    k_gemm_mfma<<<dim3(ND / 128, NTOK / 128), blk, 0, stream>>>(
        aplh, apll, ND, sa_out_w, (u64)l * WO, ND, sa_out_b, (u64)l * ND,
        tmp, nullptr, nullptr, ND, ND, 0, 0, dflag);
    k_ln<<<NTOK, 256, 0, stream>>>(h, tmp, ln1_g, ln1_b, (u64)l * ND, h, aplh, apll, dflag);

    // ---- cross-attention: Q from h, K/V from mem (= z_e) ----
    k_gemm_mfma<<<dim3(ND / 128, NTOK / 128), blk, 0, stream>>>(
        aplh, apll, ND, ca_in_w, (u64)l * WQKV, ND, ca_in_b, (u64)l * 3 * ND,
        qkv, nullptr, nullptr, 3 * ND, ND, 0, 0, dflag);
    k_gemm_mfma<<<dim3(2 * ND / 128, NTOK / 128), blk, 0, stream>>>(
        zplh, zpll, ND, ca_in_w, (u64)l * WQKV + (u64)ND * ND, ND,
        ca_in_b, (u64)l * 3 * ND + ND,
        qkv + ND, nullptr, nullptr, 3 * ND, ND, 0, 0, dflag);
    k_flash<<<dim3(NS / 64, NB * NH), blk, 0, stream>>>(qkv, padf, aplh, apll, 0);
    k_gemm_mfma<<<dim3(ND / 128, NTOK / 128), blk, 0, stream>>>(
        aplh, apll, ND, ca_out_w, (u64)l * WO, ND, ca_out_b, (u64)l * ND,
        tmp, nullptr, nullptr, ND, ND, 0, 0, dflag);
    k_ln<<<NTOK, 256, 0, stream>>>(h, tmp, ln2_g, ln2_b, (u64)l * ND, h, aplh, apll, dflag);

    // ---- feed-forward: ff1 -> relu planes (in qkv region), ff2 -> tmp ----
    k_gemm_mfma<<<dim3(NF / 128, NTOK / 128), blk, 0, stream>>>(
        aplh, apll, ND, ff_w1, (u64)l * WF1, ND, ff_b1, (u64)l * NF,
        nullptr, fplh, fpll, NF, ND, 1, 2, dflag);
    k_gemm_mfma<<<dim3(ND / 128, NTOK / 128), blk, 0, stream>>>(
        fplh, fpll, NF, ff_w2, (u64)l * WF2, NF, ff_b2, (u64)l * ND,
        tmp, nullptr, nullptr, ND, NF, 0, 0, dflag);
    k_ln<<<NTOK, 256, 0, stream>>>(h, tmp, ln3_g, ln3_b, (u64)l * ND, h, aplh, apll, dflag);
  }

  // ---- final projection -> output in input dtype ----
  k_gemm_mfma<<<dim3(ND / 128, NTOK / 128), blk, 0, stream>>>(
      aplh, apll, ND, out_w, 0, ND, out_b, 0,
      d_out, nullptr, nullptr, ND, ND, 0, 1, dflag);
}

// Round 5
// 7302.551 us; speedup vs baseline: 2.9422x; 1.4585x over previous
//
#include <hip/hip_runtime.h>
#include <math.h>

// ---------------------------------------------------------------------------
// Model_49675591746044: VQ + 6-layer post-LN transformer decoder.
// Round 9: k_flash -> bf16 MFMA flash attention. qkv GEMMs emit hi/lo planes
// (outMode 2); flash computes S = Qh*Kh + Ql*Kh + Qh*Kl (fp32-accurate) and
// O = P_bf16 * Vh via 16x16x32 MFMA, online softmax in registers per
// 16-lane group. Q/K LDS rows padded to 208 B (16B-aligned, ~2-way banks);
// V^T stored [96][40]. Everything else carried from the round-8 passing
// kernel (VQ MFMA pipeline, k_gemm_mfma, LN, planes plumbing).
// ---------------------------------------------------------------------------

#define THREEFRY_PARTITIONABLE 1

typedef unsigned short u16;
typedef unsigned int   u32;
typedef unsigned long long u64;

typedef short bf16x8 __attribute__((ext_vector_type(8)));
typedef float f32x4  __attribute__((ext_vector_type(4)));
typedef u16   u16x8  __attribute__((ext_vector_type(8)));
typedef u16   u16x4  __attribute__((ext_vector_type(4)));

constexpr int NB  = 16;
constexpr int NS  = 512;
constexpr int ND  = 768;
constexpr int NK  = 8192;
constexpr int NH  = 8;
constexpr int NL  = 6;
constexpr int NF  = 2048;
constexpr int NTOK = NB * NS;   // 8192
constexpr int NDH  = ND / NH;   // 96
#define NEGV (-1e9f)

// VQ MFMA kernel geometry
constexpr int VQ_SPLIT = 4;
constexpr int VQ_CPS   = NK / VQ_SPLIT;
constexpr int VQ_TILES = VQ_CPS / 128;

// LDS byte offsets for k_vq_score (rows padded 64->72 elems = 144 B)
constexpr int L_ALO = 4608;
constexpr int L_B   = 9216;
constexpr int L_SC  = 27648;
constexpr int L_TOT = 44032;

// LDS byte offsets for k_gemm_mfma (rows of 32 bf16 = 64 B, 128 rows/plane)
constexpr int GAH = 0;
constexpr int GAL = 8192;
constexpr int GBH = 16384;
constexpr int GBL = 24576;
constexpr int GTOT = 32768 + 8192;   // 40960

// LDS byte offsets for k_flash (Q/K rows 104 elems = 208 B; V^T/P rows 80 B)
constexpr int FQH = 0;                 // Qh [64][104]  = 13312
constexpr int FQL = 13312;             // Ql            = 13312
constexpr int FKH = 26624;             // Kh [32][104]  = 6656
constexpr int FKL = 33280;             // Kl            = 6656
constexpr int FVT = 39936;             // Vh^T [96][40] = 7680
constexpr int FP  = 47616;             // P [64][40]    = 5120
constexpr int FKB = 52736;             // kbias f32[32] = 128
constexpr int FTOT = 52864;

__device__ __forceinline__ float b2f(u16 u) { return __uint_as_float(((u32)u) << 16); }
__device__ __forceinline__ u16 f2b(float f) {
  u32 u = __float_as_uint(f);
  u32 r = (u + 0x7FFFu + ((u >> 16) & 1u)) >> 16;
  return (u16)r;
}
__device__ __forceinline__ float ldv(const void* p, size_t i, int isbf) {
  return isbf ? b2f(((const u16*)p)[i]) : ((const float*)p)[i];
}

// ---------------- dtype detection ----------------
__global__ void k_detect(const void* x, int* flag) {
  if (threadIdx.x == 0 && blockIdx.x == 0) {
    const u16* p = (const u16*)x;
    int wild = 0;
    for (int i = 0; i < 1024; i++) {
      u16 u = p[i];
      u32 e = (u >> 7) & 0xFF;
      if (!(u == 0 || u == 0x8000u || (e >= 100 && e <= 134))) wild++;
    }
    *flag = (wild < 64) ? 1 : 0;   // 1 = bf16 inputs
  }
}

// ---------------- reductions (blockDim.x == 256) ----------------
__device__ __forceinline__ float blockReduceSum256(float v, float* s) {
  int t = threadIdx.x;
  s[t] = v; __syncthreads();
  #pragma unroll
  for (int off = 128; off > 0; off >>= 1) {
    if (t < off) s[t] += s[t + off];
    __syncthreads();
  }
  float r = s[0]; __syncthreads();
  return r;
}

// ---------------- pad mask + z_e (fp32) + hi/lo bf16 planes ----------------
__global__ __launch_bounds__(256) void k_pad_z(
    const void* __restrict__ x, float* __restrict__ z,
    float* __restrict__ xn2, int* __restrict__ padf,
    u16* __restrict__ zh, u16* __restrict__ zl,
    const int* __restrict__ flag) {
  __shared__ float sred[256];
  int r = blockIdx.x, t = threadIdx.x;
  int isbf = *flag;
  size_t base = (size_t)r * ND;
  float a0 = ldv(x, base + t, isbf);
  float a1 = ldv(x, base + t + 256, isbf);
  float a2 = ldv(x, base + t + 512, isbf);
  float ss = blockReduceSum256(a0 * a0 + a1 * a1 + a2 * a2, sred);
  int pad = (sqrtf(ss) <= 1e-6f) ? 1 : 0;
  if (pad) { a0 = 0.f; a1 = 0.f; a2 = 0.f; }
  float* zr = z + base;
  zr[t] = a0; zr[t + 256] = a1; zr[t + 512] = a2;
  u16 h0 = f2b(a0), h1 = f2b(a1), h2 = f2b(a2);
  zh[base + t] = h0; zh[base + t + 256] = h1; zh[base + t + 512] = h2;
  zl[base + t]       = f2b(a0 - b2f(h0));
  zl[base + t + 256] = f2b(a1 - b2f(h1));
  zl[base + t + 512] = f2b(a2 - b2f(h2));
  if (t == 0) { xn2[r] = pad ? 0.f : ss; padf[r] = pad; }
}

// ---------------- codebook -> fp32 copy + bf16 copy + |c|^2 ----------------
__global__ __launch_bounds__(256) void k_cb(
    const void* __restrict__ cb, float* __restrict__ cbf, float* __restrict__ cn2,
    u16* __restrict__ cbh, const int* __restrict__ flag) {
  __shared__ float sred[256];
  int r = blockIdx.x, t = threadIdx.x;
  int isbf = *flag;
  size_t base = (size_t)r * ND;
  float a0 = ldv(cb, base + t, isbf);
  float a1 = ldv(cb, base + t + 256, isbf);
  float a2 = ldv(cb, base + t + 512, isbf);
  float* o = cbf + base;
  o[t] = a0; o[t + 256] = a1; o[t + 512] = a2;
  cbh[base + t] = f2b(a0); cbh[base + t + 256] = f2b(a1); cbh[base + t + 512] = f2b(a2);
  float ss = blockReduceSum256(a0 * a0 + a1 * a1 + a2 * a2, sred);
  if (t == 0) cn2[r] = ss;
}

// ---------------- top-16 insertion (running worst at wslot) ----------------
#define VQ_INSERT(dt, kk)                                                    \
  if ((dt) < wv) {                                                           \
    _Pragma("unroll")                                                        \
    for (int j = 0; j < 16; j++)                                             \
      if (j == wslot) { bestv[j] = (dt); besti[j] = (kk); }                  \
    wv = bestv[0]; wslot = 0;                                                \
    _Pragma("unroll")                                                        \
    for (int j = 1; j < 16; j++)                                             \
      if (bestv[j] > wv) { wv = bestv[j]; wslot = j; }                       \
  }

// ---------------- VQ scores via bf16 MFMA, fused top-16 --------------------
__global__ __launch_bounds__(256) void k_vq_score(
    const u16* __restrict__ xhi, const u16* __restrict__ xlo,
    const u16* __restrict__ cbh, const float* __restrict__ cn2,
    const int* __restrict__ flag,
    float* __restrict__ candv, int* __restrict__ candi) {
  __shared__ __align__(16) char lds[L_TOT];
  const int t = threadIdx.x;
  const int l = t & 63, w = t >> 6;
  const int rowbase = blockIdx.x * 32;
  const int split = blockIdx.y;
  const int dolo = (*flag) == 0;

  const int arow = t >> 3, aslot = t & 7;
  const size_t srcA = (size_t)(rowbase + arow) * ND + aslot * 8;
  const int dstA = arow * 144 + aslot * 16;
  const int c0 = (t >> 3), c1 = 32 + c0, c2 = 64 + c0, c3 = 96 + c0;
  const int dstB0 = L_B + c0 * 144 + aslot * 16;
  const int dstB1 = L_B + c1 * 144 + aslot * 16;
  const int dstB2 = L_B + c2 * 144 + aslot * 16;
  const int dstB3 = L_B + c3 * 144 + aslot * 16;

  int aoff[2][2], boff[2][2];
  #pragma unroll
  for (int mi = 0; mi < 2; mi++)
    #pragma unroll
    for (int ks = 0; ks < 2; ks++)
      aoff[mi][ks] = (mi * 16 + (l & 15)) * 144 + (ks * 4 + (l >> 4)) * 16;
  #pragma unroll
  for (int ni = 0; ni < 2; ni++)
    #pragma unroll
    for (int ks = 0; ks < 2; ks++)
      boff[ni][ks] = L_B + (w * 32 + ni * 16 + (l & 15)) * 144 + (ks * 4 + (l >> 4)) * 16;

  float* scores = (float*)(lds + L_SC);

  float bestv[16]; int besti[16];
  #pragma unroll
  for (int j = 0; j < 16; j++) { bestv[j] = 3.4e38f; besti[j] = 0; }
  float wv = 3.4e38f; int wslot = 0;

  for (int tile = 0; tile < VQ_TILES; tile++) {
    const int codebase = split * VQ_CPS + tile * 128;
    f32x4 acc[2][2];
    #pragma unroll
    for (int ni = 0; ni < 2; ni++) {
      float cv = -0.5f * cn2[codebase + w * 32 + ni * 16 + (l & 15)];
      f32x4 ini = {cv, cv, cv, cv};
      acc[0][ni] = ini; acc[1][ni] = ini;
    }
    const u16* pB0 = cbh + (size_t)(codebase + c0) * ND + aslot * 8;
    const u16* pB1 = cbh + (size_t)(codebase + c1) * ND + aslot * 8;
    const u16* pB2 = cbh + (size_t)(codebase + c2) * ND + aslot * 8;
    const u16* pB3 = cbh + (size_t)(codebase + c3) * ND + aslot * 8;

    for (int kc = 0; kc < 12; kc++) {
      const int ko = kc * 64;
      u16x8 vah = *(const u16x8*)(xhi + srcA + ko);
      u16x8 valr = {};
      if (dolo) valr = *(const u16x8*)(xlo + srcA + ko);
      u16x8 vb0 = *(const u16x8*)(pB0 + ko);
      u16x8 vb1 = *(const u16x8*)(pB1 + ko);
      u16x8 vb2 = *(const u16x8*)(pB2 + ko);
      u16x8 vb3 = *(const u16x8*)(pB3 + ko);
      __syncthreads();
      *(u16x8*)(lds + dstA) = vah;
      if (dolo) *(u16x8*)(lds + L_ALO + dstA) = valr;
      *(u16x8*)(lds + dstB0) = vb0;
      *(u16x8*)(lds + dstB1) = vb1;
      *(u16x8*)(lds + dstB2) = vb2;
      *(u16x8*)(lds + dstB3) = vb3;
      __syncthreads();
      #pragma unroll
      for (int ks = 0; ks < 2; ks++) {
        bf16x8 b0  = *(const bf16x8*)(lds + boff[0][ks]);
        bf16x8 b1  = *(const bf16x8*)(lds + boff[1][ks]);
        bf16x8 ah0 = *(const bf16x8*)(lds + aoff[0][ks]);
        bf16x8 ah1 = *(const bf16x8*)(lds + aoff[1][ks]);
        acc[0][0] = __builtin_amdgcn_mfma_f32_16x16x32_bf16(ah0, b0, acc[0][0], 0, 0, 0);
        acc[1][0] = __builtin_amdgcn_mfma_f32_16x16x32_bf16(ah1, b0, acc[1][0], 0, 0, 0);
        acc[0][1] = __builtin_amdgcn_mfma_f32_16x16x32_bf16(ah0, b1, acc[0][1], 0, 0, 0);
        acc[1][1] = __builtin_amdgcn_mfma_f32_16x16x32_bf16(ah1, b1, acc[1][1], 0, 0, 0);
        if (dolo) {
          bf16x8 al0 = *(const bf16x8*)(lds + L_ALO + aoff[0][ks]);
          bf16x8 al1 = *(const bf16x8*)(lds + L_ALO + aoff[1][ks]);
          acc[0][0] = __builtin_amdgcn_mfma_f32_16x16x32_bf16(al0, b0, acc[0][0], 0, 0, 0);
          acc[1][0] = __builtin_amdgcn_mfma_f32_16x16x32_bf16(al1, b0, acc[1][0], 0, 0, 0);
          acc[0][1] = __builtin_amdgcn_mfma_f32_16x16x32_bf16(al0, b1, acc[0][1], 0, 0, 0);
          acc[1][1] = __builtin_amdgcn_mfma_f32_16x16x32_bf16(al1, b1, acc[1][1], 0, 0, 0);
        }
      }
    }
    #pragma unroll
    for (int mi = 0; mi < 2; mi++)
      #pragma unroll
      for (int ni = 0; ni < 2; ni++)
        #pragma unroll
        for (int r = 0; r < 4; r++) {
          int srow = mi * 16 + (l >> 4) * 4 + r;
          int scol = w * 32 + ni * 16 + (l & 15);
          scores[srow * 128 + scol] = -2.0f * acc[mi][ni][r];
        }
    __syncthreads();
    {
      int irow = t >> 3, isub = t & 7;
      const float* srow = scores + irow * 128;
      #pragma unroll
      for (int i = 0; i < 16; i++) {
        int c = isub + i * 8;
        float key = srow[c];
        int gk = codebase + c;
        VQ_INSERT(key, gk)
      }
    }
    __syncthreads();
  }

  float* svals = (float*)lds;
  int*   sidx  = (int*)(lds + 16384);
  {
    int irow = t >> 3, isub = t & 7;
    #pragma unroll
    for (int j = 0; j < 16; j++) {
      svals[irow * 128 + isub * 16 + j] = bestv[j];
      sidx [irow * 128 + isub * 16 + j] = besti[j];
    }
  }
  __syncthreads();
  if (t < 32) {
    float bv[16]; int bi[16]; float w2 = 3.4e38f; int ws2 = 0;
    #pragma unroll
    for (int j = 0; j < 16; j++) { bv[j] = 3.4e38f; bi[j] = 0; }
    const float* sv = svals + t * 128;
    const int*   si = sidx  + t * 128;
    for (int i = 0; i < 128; i++) {
      float dv = sv[i];
      if (dv < w2) {
        int ii = si[i];
        #pragma unroll
        for (int j = 0; j < 16; j++)
          if (j == ws2) { bv[j] = dv; bi[j] = ii; }
        w2 = bv[0]; ws2 = 0;
        #pragma unroll
        for (int j = 1; j < 16; j++)
          if (bv[j] > w2) { w2 = bv[j]; ws2 = j; }
      }
    }
    float* ov = candv + ((size_t)(rowbase + t) * VQ_SPLIT + split) * 16;
    int*   oi = candi + ((size_t)(rowbase + t) * VQ_SPLIT + split) * 16;
    #pragma unroll
    for (int j = 0; j < 16; j++) { ov[j] = bv[j]; oi[j] = bi[j]; }
  }
}

// ---------------- merge across splits: 64 candidates -> 16 ----------------
__global__ __launch_bounds__(256) void k_vq_merge(
    const float* __restrict__ candv, const int* __restrict__ candi,
    int* __restrict__ cand) {
  int row = blockIdx.x * 256 + threadIdx.x;
  float bestv[16]; int besti[16];
  #pragma unroll
  for (int j = 0; j < 16; j++) { bestv[j] = 3.4e38f; besti[j] = 0; }
  float wv = 3.4e38f; int wslot = 0;
  const float* sv = candv + (size_t)row * 64;
  const int*   si = candi + (size_t)row * 64;
  for (int i = 0; i < 64; i++) {
    float dv = sv[i]; int ii = si[i];
    VQ_INSERT(dv, ii)
  }
  int* o = cand + (size_t)row * 16;
  #pragma unroll
  for (int j = 0; j < 16; j++) o[j] = besti[j];
}

// ---------------- threefry2x32, key (0, 42) ----------------
__device__ __forceinline__ void threefry2x32_042(u32 c0, u32 c1, u32& o0, u32& o1) {
  const u32 K0 = 0u, K1 = 42u, K2 = 0u ^ 42u ^ 0x1BD11BDAu;
  u32 x0 = c0 + K0, x1 = c1 + K1;
  #define TF_R(r) { x0 += x1; x1 = (x1 << (r)) | (x1 >> (32 - (r))); x1 ^= x0; }
  TF_R(13) TF_R(15) TF_R(26) TF_R(6)   x0 += K1; x1 += K2 + 1u;
  TF_R(17) TF_R(29) TF_R(16) TF_R(24)  x0 += K2; x1 += K0 + 2u;
  TF_R(13) TF_R(15) TF_R(26) TF_R(6)   x0 += K0; x1 += K1 + 3u;
  TF_R(17) TF_R(29) TF_R(16) TF_R(24)  x0 += K1; x1 += K2 + 4u;
  TF_R(13) TF_R(15) TF_R(26) TF_R(6)   x0 += K2; x1 += K0 + 5u;
  #undef TF_R
  o0 = x0; o1 = x1;
}

__device__ __forceinline__ u32 jax_bits(u32 e) {
  u32 b0, b1;
#if THREEFRY_PARTITIONABLE
  threefry2x32_042(0u, e, b0, b1);
  return b0 ^ b1;
#else
  const u32 HALF = (u32)(NTOK * 10 / 2);
  if (e < HALF) { threefry2x32_042(e, e + HALF, b0, b1); return b0; }
  else          { threefry2x32_042(e - HALF, e, b0, b1); return b1; }
#endif
}

// ---------------- VQ refine (fp64) + gumbel choose + write quantized --------
__global__ __launch_bounds__(64) void k_vq_choose(
    const float* __restrict__ z, const float* __restrict__ cbf,
    const int* __restrict__ cand, float* __restrict__ h,
    u16* __restrict__ oh, u16* __restrict__ ol) {
  __shared__ double s_xc[64], s_c2[64];
  __shared__ double dvals[16]; __shared__ int didx[16];
  __shared__ int s_enc;
  __shared__ double s_x2v;
  int r = blockIdx.x, t = threadIdx.x;
  int c = t >> 2, p = t & 3;
  int idx = cand[(size_t)r * 16 + c];
  const float* xr = z + (size_t)r * ND;
  const float* cr = cbf + (size_t)idx * ND;
  double xc = 0.0, c2 = 0.0;
  for (int d = p * 192; d < p * 192 + 192; d++) {
    double xv = (double)xr[d], cv = (double)cr[d];
    xc += xv * cv; c2 += cv * cv;
  }
  s_xc[t] = xc; s_c2[t] = c2;
  __syncthreads();
  if (t == 0) {
    double sx2 = 0;
    for (int d = 0; d < ND; d++) { double xv = (double)xr[d]; sx2 += xv * xv; }
    s_x2v = sx2;
  }
  __syncthreads();
  if (t < 16) {
    double sxc = 0, sc2 = 0;
    for (int pp = 0; pp < 4; pp++) { sxc += s_xc[t * 4 + pp]; sc2 += s_c2[t * 4 + pp]; }
    dvals[t] = s_x2v + sc2 - 2.0 * sxc;
    didx[t]  = cand[(size_t)r * 16 + t];
  }
  __syncthreads();
  if (t == 0) {
    double dv[16]; int di[16];
    for (int j = 0; j < 16; j++) { dv[j] = dvals[j]; di[j] = didx[j]; }
    for (int a = 1; a < 16; a++) {
      double vv = dv[a]; int ii = di[a]; int b = a;
      while (b > 0 && (dv[b-1] > vv || (dv[b-1] == vv && di[b-1] > ii))) {
        dv[b] = dv[b-1]; di[b] = di[b-1]; b--;
      }
      dv[b] = vv; di[b] = ii;
    }
    double bestsc = -1e300; int bestj = 0;
    for (int j = 0; j < 10; j++) {
      u32 e = (u32)(r * 10 + j);
      u32 bits = jax_bits(e);
      u32 fb = (bits >> 9) | 0x3f800000u;
      float uf = __uint_as_float(fb) - 1.0f;
      float vf = uf + 1e-10f;
      vf = fmaxf(1e-10f, vf);
      double g = -log(-log((double)vf));
      double sc = -dv[j] + g;
      if (sc > bestsc) { bestsc = sc; bestj = j; }
    }
    s_enc = di[bestj];
  }
  __syncthreads();
  int enc = s_enc;
  const float* qv = cbf + (size_t)enc * ND;
  float* hr = h + (size_t)r * ND;
  size_t base = (size_t)r * ND;
  for (int d = t; d < ND; d += 64) {
    float v = qv[d];
    hr[d] = v;
    u16 hv = f2b(v);
    oh[base + d] = hv;
    ol[base + d] = f2b(v - b2f(hv));
  }
}

// ---------------- MFMA GEMM: C = A[M,K] * B[N,K]^T + bias -------------------
// outMode: 0 = fp32 Cv; 1 = input dtype Cv; 2 = hi/lo planes Chi/Clo.
__global__ __launch_bounds__(256) void k_gemm_mfma(
    const u16* __restrict__ Ah, const u16* __restrict__ Al, int lda,
    const void* __restrict__ Bw, u64 boffx, int ldb,
    const void* __restrict__ bias, u64 bioff,
    void* __restrict__ Cv, u16* __restrict__ Chi, u16* __restrict__ Clo, int ldc,
    int Kd, int relu, int outMode, const int* __restrict__ flag) {
  __shared__ __align__(16) char lds[GTOT];
  const int t = threadIdx.x, l = t & 63, w = t >> 6;
  const int wm = w >> 1, wn = w & 1;
  const int m0 = blockIdx.y * 128, n0 = blockIdx.x * 128;
  const int isbf = *flag;
  const u16*   b16 = (const u16*)Bw + boffx;
  const float* b32 = (const float*)Bw + boffx;

  const int i0 = (w * 2 + 0) * 64 + l, i1 = (w * 2 + 1) * 64 + l;
  const u16* sAh0 = Ah + (size_t)(m0 + (i0 >> 2)) * lda + (i0 & 3) * 8;
  const u16* sAh1 = Ah + (size_t)(m0 + (i1 >> 2)) * lda + (i1 & 3) * 8;
  const u16* sAl0 = Al + (size_t)(m0 + (i0 >> 2)) * lda + (i0 & 3) * 8;
  const u16* sAl1 = Al + (size_t)(m0 + (i1 >> 2)) * lda + (i1 & 3) * 8;
  const u16* sB0  = b16 + (size_t)(n0 + (i0 >> 2)) * ldb + (i0 & 3) * 8;
  const u16* sB1  = b16 + (size_t)(n0 + (i1 >> 2)) * ldb + (i1 & 3) * 8;
  const int wo = __builtin_amdgcn_readfirstlane(w * 2048);

  const int brow = t >> 1, bko = (t & 1) * 16;
  const float* sBf = b32 + (size_t)(n0 + brow) * ldb + bko;
  const int dBw = brow * 64 + bko * 2;

  int aro[4], bro[4];
  #pragma unroll
  for (int mi = 0; mi < 4; mi++)
    aro[mi] = (wm * 64 + mi * 16 + (l & 15)) * 64 + (l >> 4) * 16;
  #pragma unroll
  for (int ni = 0; ni < 4; ni++)
    bro[ni] = (wn * 64 + ni * 16 + (l & 15)) * 64 + (l >> 4) * 16;

  f32x4 acc[4][4];
  #pragma unroll
  for (int ni = 0; ni < 4; ni++) {
    float bv = ldv(bias, bioff + n0 + wn * 64 + ni * 16 + (l & 15), isbf);
    f32x4 ini = {bv, bv, bv, bv};
    #pragma unroll
    for (int mi = 0; mi < 4; mi++) acc[mi][ni] = ini;
  }

  const int nkt = Kd >> 5;
  for (int kt = 0; kt < nkt; kt++) {
    float bf[16];
    if (!isbf) {
      #pragma unroll
      for (int q = 0; q < 4; q++) {
        float4 fv = *(const float4*)(sBf + q * 4);
        bf[q * 4 + 0] = fv.x; bf[q * 4 + 1] = fv.y;
        bf[q * 4 + 2] = fv.z; bf[q * 4 + 3] = fv.w;
      }
    }
    __syncthreads();
    __builtin_amdgcn_global_load_lds((const __attribute__((address_space(1))) unsigned int*)sAh0,
        (__attribute__((address_space(3))) unsigned int*)(lds + GAH + wo), 16, 0, 0);
    __builtin_amdgcn_global_load_lds((const __attribute__((address_space(1))) unsigned int*)sAh1,
        (__attribute__((address_space(3))) unsigned int*)(lds + GAH + wo + 1024), 16, 0, 0);
    __builtin_amdgcn_global_load_lds((const __attribute__((address_space(1))) unsigned int*)sAl0,
        (__attribute__((address_space(3))) unsigned int*)(lds + GAL + wo), 16, 0, 0);
    __builtin_amdgcn_global_load_lds((const __attribute__((address_space(1))) unsigned int*)sAl1,
        (__attribute__((address_space(3))) unsigned int*)(lds + GAL + wo + 1024), 16, 0, 0);
    if (isbf) {
      __builtin_amdgcn_global_load_lds((const __attribute__((address_space(1))) unsigned int*)sB0,
          (__attribute__((address_space(3))) unsigned int*)(lds + GBH + wo), 16, 0, 0);
      __builtin_amdgcn_global_load_lds((const __attribute__((address_space(1))) unsigned int*)sB1,
          (__attribute__((address_space(3))) unsigned int*)(lds + GBH + wo + 1024), 16, 0, 0);
    } else {
      u16x8 h0, h1, l0v, l1v;
      #pragma unroll
      for (int j = 0; j < 8; j++) {
        u16 hv = f2b(bf[j]);     h0[j] = (short)hv;  l0v[j] = (short)f2b(bf[j] - b2f(hv));
        u16 hw = f2b(bf[8 + j]); h1[j] = (short)hw;  l1v[j] = (short)f2b(bf[8 + j] - b2f(hw));
      }
      *(u16x8*)(lds + GBH + dBw)      = h0;
      *(u16x8*)(lds + GBH + dBw + 16) = h1;
      *(u16x8*)(lds + GBL + dBw)      = l0v;
      *(u16x8*)(lds + GBL + dBw + 16) = l1v;
    }
    __syncthreads();

    bf16x8 ah[4], al[4];
    #pragma unroll
    for (int mi = 0; mi < 4; mi++) {
      ah[mi] = *(const bf16x8*)(lds + GAH + aro[mi]);
      al[mi] = *(const bf16x8*)(lds + GAL + aro[mi]);
    }
    #pragma unroll
    for (int ni = 0; ni < 4; ni++) {
      bf16x8 bh = *(const bf16x8*)(lds + GBH + bro[ni]);
      #pragma unroll
      for (int mi = 0; mi < 4; mi++)
        acc[mi][ni] = __builtin_amdgcn_mfma_f32_16x16x32_bf16(ah[mi], bh, acc[mi][ni], 0, 0, 0);
      #pragma unroll
      for (int mi = 0; mi < 4; mi++)
        acc[mi][ni] = __builtin_amdgcn_mfma_f32_16x16x32_bf16(al[mi], bh, acc[mi][ni], 0, 0, 0);
      if (!isbf) {
        bf16x8 bl = *(const bf16x8*)(lds + GBL + bro[ni]);
        #pragma unroll
        for (int mi = 0; mi < 4; mi++)
          acc[mi][ni] = __builtin_amdgcn_mfma_f32_16x16x32_bf16(ah[mi], bl, acc[mi][ni], 0, 0, 0);
      }
    }
    sAh0 += 32; sAh1 += 32; sAl0 += 32; sAl1 += 32;
    sB0 += 32; sB1 += 32; sBf += 32;
  }

  #pragma unroll
  for (int mi = 0; mi < 4; mi++)
    #pragma unroll
    for (int ni = 0; ni < 4; ni++) {
      int col = n0 + wn * 64 + ni * 16 + (l & 15);
      #pragma unroll
      for (int r = 0; r < 4; r++) {
        int row = m0 + wm * 64 + mi * 16 + (l >> 4) * 4 + r;
        float v = acc[mi][ni][r];
        if (relu) v = fmaxf(v, 0.f);
        size_t ci = (size_t)row * ldc + col;
        if (outMode == 0) {
          ((float*)Cv)[ci] = v;
        } else if (outMode == 1) {
          if (isbf) ((u16*)Cv)[ci] = f2b(v);
          else      ((float*)Cv)[ci] = v;
        } else {
          u16 hv = f2b(v);
          Chi[ci] = hv;
          Clo[ci] = f2b(v - b2f(hv));
        }
      }
    }
}

// ---------------- MFMA flash attention -------------------------------------
// qkv given as hi/lo bf16 planes [NTOK][3*ND]. Per block: 64 queries, one
// (b,h); KV tiles of 32. S = Qh*Kh + Ql*Kh + Qh*Kl; O = P_bf16 * Vh.
// Online softmax in registers per 16-lane group (4 query rows each).
__global__ __launch_bounds__(256) void k_flash(
    const u16* __restrict__ qh, const u16* __restrict__ ql,
    const int* __restrict__ padf,
    u16* __restrict__ oh, u16* __restrict__ ol, int selfmask) {
  __shared__ __align__(16) char lds[FTOT];
  const int zb = blockIdx.y, b = zb >> 3, hh = zb & 7;
  const int m0 = blockIdx.x * 64;
  const int t = threadIdx.x, l = t & 63, w = t >> 6;
  const int r16 = l & 15, hi4 = l >> 4;
  const size_t qr = 3 * ND;
  const u16* Qhb = qh + (size_t)(b * NS) * qr + hh * NDH;
  const u16* Qlb = ql + (size_t)(b * NS) * qr + hh * NDH;
  const u16* Khb = Qhb + ND;
  const u16* Klb = Qlb + ND;
  const u16* Vhb = Qhb + 2 * ND;

  // ---- stage Q once: thread q=t>>2, part=t&3 (24 u16 = 3 x u16x8)
  {
    int q = t >> 2, part = t & 3;
    const u16* sqh = Qhb + (size_t)(m0 + q) * qr + part * 24;
    const u16* sql = Qlb + (size_t)(m0 + q) * qr + part * 24;
    char* dqh = lds + FQH + q * 208 + part * 48;
    char* dql = lds + FQL + q * 208 + part * 48;
    #pragma unroll
    for (int j = 0; j < 3; j++) {
      *(u16x8*)(dqh + j * 16) = *(const u16x8*)(sqh + j * 8);
      *(u16x8*)(dql + j * 16) = *(const u16x8*)(sql + j * 8);
    }
  }

  f32x4 oacc[6];
  #pragma unroll
  for (int ni = 0; ni < 6; ni++) { f32x4 zz = {0.f,0.f,0.f,0.f}; oacc[ni] = zz; }
  float m_run[4], l_run[4];
  #pragma unroll
  for (int r = 0; r < 4; r++) { m_run[r] = -3.0e38f; l_run[r] = 0.f; }
  const float isq = 1.0f / sqrtf(96.0f);

  // K/V staging mapping: key = t&31, part = t>>5 (12 u16 = 3 x u16x4)
  const int skey = t & 31, spart = t >> 5;
  float* kbias = (float*)(lds + FKB);

  for (int kt = 0; kt < NS; kt += 32) {
    // issue global loads
    const u16* skh = Khb + (size_t)(kt + skey) * qr + spart * 12;
    const u16* skl = Klb + (size_t)(kt + skey) * qr + spart * 12;
    const u16* svh = Vhb + (size_t)(kt + skey) * qr + spart * 12;
    u16x4 kh[3], klv[3], vh[3];
    #pragma unroll
    for (int j = 0; j < 3; j++) {
      kh[j]  = *(const u16x4*)(skh + j * 4);
      klv[j] = *(const u16x4*)(skl + j * 4);
      vh[j]  = *(const u16x4*)(svh + j * 4);
    }
    float kbv = 0.f;
    if (t < 32) kbv = padf[b * NS + kt + t] ? NEGV : 0.f;
    __syncthreads();   // all waves done reading previous K/V
    {
      char* dk = lds + FKH + skey * 208 + spart * 24;
      char* dl = lds + FKL + skey * 208 + spart * 24;
      #pragma unroll
      for (int j = 0; j < 3; j++) {
        *(u16x4*)(dk + j * 8) = kh[j];
        *(u16x4*)(dl + j * 8) = klv[j];
      }
      #pragma unroll
      for (int j = 0; j < 12; j++) {
        int d = spart * 12 + (j >> 2) * 4 + (j & 3);
        *(u16*)(lds + FVT + d * 80 + skey * 2) = vh[j >> 2][j & 3];
      }
      if (t < 32) kbias[t] = kbv;
    }
    __syncthreads();   // staging visible

    // ---- QK^T: S[16 q][32 k] per wave
    f32x4 sacc[2];
    { f32x4 zz = {0.f,0.f,0.f,0.f}; sacc[0] = zz; sacc[1] = zz; }
    #pragma unroll
    for (int ks = 0; ks < 3; ks++) {
      const int ko = hi4 * 16 + ks * 64;
      bf16x8 qhf = *(const bf16x8*)(lds + FQH + (w * 16 + r16) * 208 + ko);
      bf16x8 qlf = *(const bf16x8*)(lds + FQL + (w * 16 + r16) * 208 + ko);
      #pragma unroll
      for (int n = 0; n < 2; n++) {
        bf16x8 khf = *(const bf16x8*)(lds + FKH + (n * 16 + r16) * 208 + ko);
        bf16x8 klf = *(const bf16x8*)(lds + FKL + (n * 16 + r16) * 208 + ko);
        sacc[n] = __builtin_amdgcn_mfma_f32_16x16x32_bf16(qhf, khf, sacc[n], 0, 0, 0);
        sacc[n] = __builtin_amdgcn_mfma_f32_16x16x32_bf16(qlf, khf, sacc[n], 0, 0, 0);
        sacc[n] = __builtin_amdgcn_mfma_f32_16x16x32_bf16(qhf, klf, sacc[n], 0, 0, 0);
      }
    }

    // ---- softmax (per 16-lane group: rows hi4*4+r)
    float kb0 = kbias[r16], kb1 = kbias[r16 + 16];
    float alpha[4];
    #pragma unroll
    for (int r = 0; r < 4; r++) {
      int qg = m0 + w * 16 + hi4 * 4 + r;
      float s0 = sacc[0][r] * isq + kb0;
      float s1 = sacc[1][r] * isq + kb1;
      if (selfmask) {
        if (kt + r16 < qg) s0 += NEGV;
        if (kt + r16 + 16 < qg) s1 += NEGV;
      }
      float mv = fmaxf(s0, s1);
      #pragma unroll
      for (int off = 1; off < 16; off <<= 1) mv = fmaxf(mv, __shfl_xor(mv, off, 16));
      float mn = fmaxf(m_run[r], mv);
      float al = expf(m_run[r] - mn);
      m_run[r] = mn;
      alpha[r] = al;
      float p0 = expf(s0 - mn), p1 = expf(s1 - mn);
      float ls = p0 + p1;
      #pragma unroll
      for (int off = 1; off < 16; off <<= 1) ls += __shfl_xor(ls, off, 16);
      l_run[r] = l_run[r] * al + ls;
      char* pr = lds + FP + (w * 16 + hi4 * 4 + r) * 80;
      *(u16*)(pr + r16 * 2) = f2b(p0);
      *(u16*)(pr + (r16 + 16) * 2) = f2b(p1);
    }
    #pragma unroll
    for (int ni = 0; ni < 6; ni++)
      #pragma unroll
      for (int r = 0; r < 4; r++) oacc[ni][r] *= alpha[r];

    // ---- PV: O += P[16 q][32 k] * Vh^T (wave-local P; compiler orders lds)
    bf16x8 pa = *(const bf16x8*)(lds + FP + (w * 16 + r16) * 80 + hi4 * 16);
    #pragma unroll
    for (int ni = 0; ni < 6; ni++) {
      bf16x8 vb = *(const bf16x8*)(lds + FVT + (r16 + ni * 16) * 80 + hi4 * 16);
      oacc[ni] = __builtin_amdgcn_mfma_f32_16x16x32_bf16(pa, vb, oacc[ni], 0, 0, 0);
    }
    __syncthreads();   // all waves done with K/V/P before next stage
  }

  // ---- epilogue: O row = q, col = d; divide by l_run; hi/lo planes out
  float invl[4];
  #pragma unroll
  for (int r = 0; r < 4; r++) invl[r] = 1.0f / l_run[r];
  #pragma unroll
  for (int ni = 0; ni < 6; ni++) {
    int d = r16 + ni * 16;
    #pragma unroll
    for (int r = 0; r < 4; r++) {
      int q = m0 + w * 16 + hi4 * 4 + r;
      float val = oacc[ni][r] * invl[r];
      size_t base = (size_t)(b * NS + q) * ND + hh * NDH + d;
      u16 hv = f2b(val);
      oh[base] = hv;
      ol[base] = f2b(val - b2f(hv));
    }
  }
}

// ---------------- LayerNorm(res + x) -> dst + hi/lo planes ----------------
__global__ __launch_bounds__(256) void k_ln(
    const float* res, const float* x,
    const void* __restrict__ g, const void* __restrict__ bb, u64 goff,
    float* dst, u16* __restrict__ oh, u16* __restrict__ ol,
    const int* __restrict__ flag) {
  __shared__ float sred[256];
  int r = blockIdx.x, t = threadIdx.x;
  int isbf = *flag;
  size_t base = (size_t)r * ND;
  const float* rr = res + base;
  const float* xr = x + base;
  float v0 = rr[t] + xr[t];
  float v1 = rr[t + 256] + xr[t + 256];
  float v2 = rr[t + 512] + xr[t + 512];
  float S = blockReduceSum256(v0 + v1 + v2, sred);
  float m = S / (float)ND;
  float d0 = v0 - m, d1 = v1 - m, d2 = v2 - m;
  float Q = blockReduceSum256(d0 * d0 + d1 * d1 + d2 * d2, sred);
  float inv = 1.0f / sqrtf(Q / (float)ND + 1e-5f);
  float* o = dst + base;
  float y0 = d0 * inv * ldv(g, goff + t, isbf)       + ldv(bb, goff + t, isbf);
  float y1 = d1 * inv * ldv(g, goff + t + 256, isbf) + ldv(bb, goff + t + 256, isbf);
  float y2 = d2 * inv * ldv(g, goff + t + 512, isbf) + ldv(bb, goff + t + 512, isbf);
  o[t] = y0; o[t + 256] = y1; o[t + 512] = y2;
  u16 h0 = f2b(y0), h1 = f2b(y1), h2 = f2b(y2);
  oh[base + t] = h0; oh[base + t + 256] = h1; oh[base + t + 512] = h2;
  ol[base + t]       = f2b(y0 - b2f(h0));
  ol[base + t + 256] = f2b(y1 - b2f(h1));
  ol[base + t + 512] = f2b(y2 - b2f(h2));
}

// ---------------------------------------------------------------------------
extern "C" void kernel_launch(void* const* d_in, const int* in_sizes, int n_in,
                              void* d_out, int out_size, void* d_ws, size_t ws_size,
                              hipStream_t stream) {
  const void* x        = d_in[0];
  const void* cb       = d_in[1];
  const void* sa_in_w  = d_in[2];
  const void* sa_in_b  = d_in[3];
  const void* sa_out_w = d_in[4];
  const void* sa_out_b = d_in[5];
  const void* ca_in_w  = d_in[6];
  const void* ca_in_b  = d_in[7];
  const void* ca_out_w = d_in[8];
  const void* ca_out_b = d_in[9];
  const void* ln1_g = d_in[10]; const void* ln1_b = d_in[11];
  const void* ln2_g = d_in[12]; const void* ln2_b = d_in[13];
  const void* ln3_g = d_in[14]; const void* ln3_b = d_in[15];
  const void* ff_w1 = d_in[16]; const void* ff_b1 = d_in[17];
  const void* ff_w2 = d_in[18]; const void* ff_b2 = d_in[19];
  const void* out_w = d_in[20]; const void* out_b = d_in[21];

  const size_t ZSZ = (size_t)NTOK * ND;
  float* ws   = (float*)d_ws;
  float* z    = ws;
  float* h    = z + ZSZ;
  float* qkv  = h + ZSZ;          // 3 ZSZ region (aliased below)
  float* big  = qkv + 3 * ZSZ;    // cbf during VQ
  float* tmp  = big + ZSZ;
  u16*   zplh = (u16*)(tmp + ZSZ);
  u16*   zpll = zplh + ZSZ;
  u16*   aplh = zpll + ZSZ;
  u16*   apll = aplh + ZSZ;
  float* xn2  = (float*)(apll + ZSZ);
  float* cn2  = xn2 + NTOK;
  int*   padf = (int*)(cn2 + NK);
  int*   cand = padf + NTOK;
  int*   dflag = cand + (size_t)NTOK * 16;
  float* cbf  = big;
  // qkv region aliases: VQ scratch -> qkv hi/lo planes -> ff planes
  u16*   cbh   = (u16*)qkv;
  float* candv = (float*)(cbh + (size_t)NK * ND);
  int*   candi = (int*)(candv + (size_t)NTOK * 64);
  u16*   qkvh  = (u16*)qkv;
  u16*   qkvl  = qkvh + 3 * ZSZ;
  u16*   fplh  = (u16*)qkv;
  u16*   fpll  = fplh + (size_t)NTOK * NF;

  dim3 blk(256);

  k_detect   <<<1, 64, 0, stream>>>(x, dflag);
  k_pad_z    <<<NTOK, 256, 0, stream>>>(x, z, xn2, padf, zplh, zpll, dflag);
  k_cb       <<<NK,   256, 0, stream>>>(cb, cbf, cn2, cbh, dflag);
  k_vq_score <<<dim3(NTOK / 32, VQ_SPLIT), 256, 0, stream>>>(zplh, zpll, cbh, cn2, dflag, candv, candi);
  k_vq_merge <<<NTOK / 256, 256, 0, stream>>>(candv, candi, cand);
  k_vq_choose<<<NTOK, 64, 0, stream>>>(z, cbf, cand, h, aplh, apll);

  const u64 WQKV = (u64)3 * ND * ND, WO = (u64)ND * ND;
  const u64 WF1 = (u64)NF * ND, WF2 = (u64)ND * NF;

  for (int l = 0; l < NL; l++) {
    // ---- self-attention ----
    k_gemm_mfma<<<dim3(3 * ND / 128, NTOK / 128), blk, 0, stream>>>(
        aplh, apll, ND, sa_in_w, (u64)l * WQKV, ND, sa_in_b, (u64)l * 3 * ND,
        nullptr, qkvh, qkvl, 3 * ND, ND, 0, 2, dflag);
    k_flash<<<dim3(NS / 64, NB * NH), blk, 0, stream>>>(qkvh, qkvl, padf, aplh, apll, 1);
    k_gemm_mfma<<<dim3(ND / 128, NTOK / 128), blk, 0, stream>>>(
        aplh, apll, ND, sa_out_w, (u64)l * WO, ND, sa_out_b, (u64)l * ND,
        tmp, nullptr, nullptr, ND, ND, 0, 0, dflag);
    k_ln<<<NTOK, 256, 0, stream>>>(h, tmp, ln1_g, ln1_b, (u64)l * ND, h, aplh, apll, dflag);

    // ---- cross-attention: Q from h, K/V from mem (= z_e) ----
    k_gemm_mfma<<<dim3(ND / 128, NTOK / 128), blk, 0, stream>>>(
        aplh, apll, ND, ca_in_w, (u64)l * WQKV, ND, ca_in_b, (u64)l * 3 * ND,
        nullptr, qkvh, qkvl, 3 * ND, ND, 0, 2, dflag);
    k_gemm_mfma<<<dim3(2 * ND / 128, NTOK / 128), blk, 0, stream>>>(
        zplh, zpll, ND, ca_in_w, (u64)l * WQKV + (u64)ND * ND, ND,
        ca_in_b, (u64)l * 3 * ND + ND,
        nullptr, qkvh + ND, qkvl + ND, 3 * ND, ND, 0, 2, dflag);
    k_flash<<<dim3(NS / 64, NB * NH), blk, 0, stream>>>(qkvh, qkvl, padf, aplh, apll, 0);
    k_gemm_mfma<<<dim3(ND / 128, NTOK / 128), blk, 0, stream>>>(
        aplh, apll, ND, ca_out_w, (u64)l * WO, ND, ca_out_b, (u64)l * ND,
        tmp, nullptr, nullptr, ND, ND, 0, 0, dflag);
    k_ln<<<NTOK, 256, 0, stream>>>(h, tmp, ln2_g, ln2_b, (u64)l * ND, h, aplh, apll, dflag);

    // ---- feed-forward ----
    k_gemm_mfma<<<dim3(NF / 128, NTOK / 128), blk, 0, stream>>>(
        aplh, apll, ND, ff_w1, (u64)l * WF1, ND, ff_b1, (u64)l * NF,
        nullptr, fplh, fpll, NF, ND, 1, 2, dflag);
    k_gemm_mfma<<<dim3(ND / 128, NTOK / 128), blk, 0, stream>>>(
        fplh, fpll, NF, ff_w2, (u64)l * WF2, NF, ff_b2, (u64)l * ND,
        tmp, nullptr, nullptr, ND, NF, 0, 0, dflag);
    k_ln<<<NTOK, 256, 0, stream>>>(h, tmp, ln3_g, ln3_b, (u64)l * ND, h, aplh, apll, dflag);
  }

  // ---- final projection -> output in input dtype ----
  k_gemm_mfma<<<dim3(ND / 128, NTOK / 128), blk, 0, stream>>>(
      aplh, apll, ND, out_w, 0, ND, out_b, 0,
      d_out, nullptr, nullptr, ND, ND, 0, 1, dflag);
}